// Round 6
// baseline (899.613 us; speedup 1.0000x reference)
//
#include <hip/hip_runtime.h>

#define S 207
#define BATCH 128
#define NPTS 256000

static const int OFFS[19] = {0,8,16,24,32,40,56,72,88,104,128,152,176,200,232,264,296,328,392};

__global__ void zero2_kernel(float4* __restrict__ a, float4* __restrict__ b, int n4) {
    int i = blockIdx.x * blockDim.x + threadIdx.x;
    if (i < n4) { a[i] = make_float4(0,0,0,0); b[i] = make_float4(0,0,0,0); }
}

__global__ void zero_kernel(float* __restrict__ p, int n) {
    int i = blockIdx.x * blockDim.x + threadIdx.x;
    if (i < n) p[i] = 0.0f;
}

__global__ void scatter_kernel(const int* __restrict__ loc, const int* __restrict__ bidx,
                               const float* __restrict__ feat,
                               float* __restrict__ xs, float* __restrict__ ms) {
    int t = blockIdx.x * blockDim.x + threadIdx.x;
    if (t >= NPTS) return;
    int b = bidx[t];
    int r = loc[2 * t];
    int c = loc[2 * t + 1];
    int idx = (b * S + r) * S + c;
    atomicAdd(&xs[idx], feat[t]);
    ms[idx] = 1.0f;
}

// Fused conv0(SAME)*m -> masked 3x2 maxpool. One thread per output pixel, all 8 channels.
__global__ __launch_bounds__(256) void conv0_pool_kernel(
    const float* __restrict__ xs, const float* __restrict__ ms,
    const float* __restrict__ w,   // (3,3,1,8)
    float* __restrict__ x1, float* __restrict__ m1) {
    const int Hout = 103;
    int opix = blockIdx.x * 256 + threadIdx.x;
    int total = BATCH * Hout * Hout;
    if (opix >= total) return;
    int wo = opix % Hout;
    int t = opix / Hout;
    int ho = t % Hout;
    int b  = t / Hout;

    float mv[3][3];
    float mwin = 0.0f;
    #pragma unroll
    for (int pi = 0; pi < 3; ++pi)
        #pragma unroll
        for (int pj = 0; pj < 3; ++pj) {
            float m = ms[(b * S + 2 * ho + pi) * S + 2 * wo + pj];
            mv[pi][pj] = m;
            mwin = fmaxf(mwin, m);
        }
    float* xp = x1 + (size_t)opix * 8;
    if (mwin <= 0.0f) {
        *(float4*)xp = make_float4(0,0,0,0);
        *(float4*)(xp + 4) = make_float4(0,0,0,0);
        m1[opix] = 0.0f;
        return;
    }
    float p[5][5];
    #pragma unroll
    for (int r = 0; r < 5; ++r) {
        int ii = 2 * ho - 1 + r;
        #pragma unroll
        for (int c = 0; c < 5; ++c) {
            int jj = 2 * wo - 1 + c;
            bool ok = ((unsigned)ii < (unsigned)S) && ((unsigned)jj < (unsigned)S);
            p[r][c] = ok ? xs[(b * S + ii) * S + jj] : 0.0f;
        }
    }
    float best[8];
    #pragma unroll
    for (int co = 0; co < 8; ++co) best[co] = -1e30f;
    #pragma unroll
    for (int pi = 0; pi < 3; ++pi)
        #pragma unroll
        for (int pj = 0; pj < 3; ++pj) {
            if (mv[pi][pj] > 0.0f) {
                float acc[8];
                #pragma unroll
                for (int co = 0; co < 8; ++co) acc[co] = 0.0f;
                #pragma unroll
                for (int kh = 0; kh < 3; ++kh)
                    #pragma unroll
                    for (int kw = 0; kw < 3; ++kw) {
                        float x = p[pi + kh][pj + kw];
                        #pragma unroll
                        for (int co = 0; co < 8; ++co)
                            acc[co] = fmaf(x, w[(kh * 3 + kw) * 8 + co], acc[co]);
                    }
                #pragma unroll
                for (int co = 0; co < 8; ++co) best[co] = fmaxf(best[co], acc[co]);
            }
        }
    *(float4*)xp = make_float4(best[0], best[1], best[2], best[3]);
    *(float4*)(xp + 4) = make_float4(best[4], best[5], best[6], best[7]);
    m1[opix] = 1.0f;
}

// Fused residual block, C=8, sparsity-compacted + float4-planar LDS.
// Masks are binary (exactly 0.0/1.0), and at 103x103 only ~35% of pixels are
// active -> the conv loops iterate a compacted active-pixel list (all lanes
// useful) instead of a divergent if(m>0) over all pixels. LDS holds pixel
// data as float4 pairs -> ds_read_b128 (18 reads/px vs 72 b32).
// Weights stay in global (2.3 KB/conv -> scalar-cache resident at C=8).
__global__ __launch_bounds__(256) void resblock8_kernel(
    const float* __restrict__ in, const float* __restrict__ mask,
    const float* __restrict__ w1, const float* __restrict__ w2,
    const float* __restrict__ g1, const float* __restrict__ bb1,
    const float* __restrict__ g2, const float* __restrict__ bb2,
    float* __restrict__ out, int H) {
    constexpr int TILE = 16, NTX = 7;
    constexpr int XT = TILE + 4, HT = TILE + 2;   // 20, 18
    constexpr int XA = XT * XT, HA = HT * HT;     // 400, 324
    constexpr int T2 = TILE * TILE;               // 256
    __shared__ float4 xsa[XA], xsb[XA];           // bnrelu1'd input (ch0-3, ch4-7)
    __shared__ float4 h1a[HA], h1b[HA];           // bnrelu2'd intermediate
    __shared__ float msh[XA];
    __shared__ unsigned short list2[HA], list3[T2];
    __shared__ int cnt2, cnt3;

    int tid = threadIdx.x;
    int bid = blockIdx.x;
    int b = bid / (NTX * NTX);
    int t = bid % (NTX * NTX);
    int r0 = (t / NTX) * TILE, c0 = (t % NTX) * TILE;

    if (tid == 0) { cnt2 = 0; cnt3 = 0; }

    float g1r[8], b1r[8];
    #pragma unroll
    for (int c = 0; c < 8; ++c) { g1r[c] = g1[c]; b1r[c] = bb1[c]; }

    // phase 1: load + bnrelu1 -> float4-planar LDS (mask is binary: m==1 if active)
    for (int i = tid; i < XA; i += 256) {
        int py = i / XT, px = i % XT;
        int gy = r0 - 2 + py, gx = c0 - 2 + px;
        bool ok = (unsigned)gy < (unsigned)H && (unsigned)gx < (unsigned)H;
        float m = 0.0f;
        if (ok) m = mask[(size_t)(b * H + gy) * H + gx];
        msh[i] = m;
        float4 va = make_float4(0,0,0,0), vb = make_float4(0,0,0,0);
        if (m > 0.0f) {
            const float* ip = in + ((size_t)(b * H + gy) * H + gx) * 8;
            float4 x0 = *(const float4*)ip;
            float4 x1 = *(const float4*)(ip + 4);
            va.x = fmaxf(fmaf(x0.x, g1r[0], b1r[0]), 0.0f);
            va.y = fmaxf(fmaf(x0.y, g1r[1], b1r[1]), 0.0f);
            va.z = fmaxf(fmaf(x0.z, g1r[2], b1r[2]), 0.0f);
            va.w = fmaxf(fmaf(x0.w, g1r[3], b1r[3]), 0.0f);
            vb.x = fmaxf(fmaf(x1.x, g1r[4], b1r[4]), 0.0f);
            vb.y = fmaxf(fmaf(x1.y, g1r[5], b1r[5]), 0.0f);
            vb.z = fmaxf(fmaf(x1.z, g1r[6], b1r[6]), 0.0f);
            vb.w = fmaxf(fmaf(x1.w, g1r[7], b1r[7]), 0.0f);
        }
        xsa[i] = va; xsb[i] = vb;
    }
    float g2r[8], b2r[8];
    #pragma unroll
    for (int c = 0; c < 8; ++c) { g2r[c] = g2[c]; b2r[c] = bb2[c]; }
    __syncthreads();

    // build compacted active lists + zero h1
    for (int i = tid; i < HA; i += 256) {
        h1a[i] = make_float4(0,0,0,0);
        h1b[i] = make_float4(0,0,0,0);
        int py = i / HT, px = i % HT;
        if (msh[(py + 1) * XT + px + 1] > 0.0f) {
            int k = atomicAdd(&cnt2, 1);
            list2[k] = (unsigned short)i;
        }
    }
    for (int i = tid; i < T2; i += 256) {
        int ty = i / TILE, tx = i % TILE;
        if (r0 + ty < H && c0 + tx < H && msh[(ty + 2) * XT + tx + 2] > 0.0f) {
            int k = atomicAdd(&cnt3, 1);
            list3[k] = (unsigned short)i;
        }
    }
    __syncthreads();

    // phase 2: conv1 over ACTIVE h-positions only; bnrelu2 fused into the store
    int n2 = cnt2;
    for (int k = tid; k < n2; k += 256) {
        int pos = list2[k];
        int py = pos / HT, px = pos % HT;
        float acc[8];
        #pragma unroll
        for (int co = 0; co < 8; ++co) acc[co] = 0.0f;
        #pragma unroll
        for (int kh = 0; kh < 3; ++kh)
            #pragma unroll
            for (int kw = 0; kw < 3; ++kw) {
                int pix = (py + kh) * XT + px + kw;
                float4 a = xsa[pix], c4 = xsb[pix];
                const float* wp = w1 + (kh * 3 + kw) * 64;   // wave-uniform -> s_load
                #pragma unroll
                for (int co = 0; co < 8; ++co) {
                    float s = fmaf(a.x,  wp[co],      acc[co]);
                    s = fmaf(a.y,  wp[8  + co], s);
                    s = fmaf(a.z,  wp[16 + co], s);
                    s = fmaf(a.w,  wp[24 + co], s);
                    s = fmaf(c4.x, wp[32 + co], s);
                    s = fmaf(c4.y, wp[40 + co], s);
                    s = fmaf(c4.z, wp[48 + co], s);
                    acc[co] = fmaf(c4.w, wp[56 + co], s);
                }
            }
        float4 ha, hb;
        ha.x = fmaxf(fmaf(acc[0], g2r[0], b2r[0]), 0.0f);
        ha.y = fmaxf(fmaf(acc[1], g2r[1], b2r[1]), 0.0f);
        ha.z = fmaxf(fmaf(acc[2], g2r[2], b2r[2]), 0.0f);
        ha.w = fmaxf(fmaf(acc[3], g2r[3], b2r[3]), 0.0f);
        hb.x = fmaxf(fmaf(acc[4], g2r[4], b2r[4]), 0.0f);
        hb.y = fmaxf(fmaf(acc[5], g2r[5], b2r[5]), 0.0f);
        hb.z = fmaxf(fmaf(acc[6], g2r[6], b2r[6]), 0.0f);
        hb.w = fmaxf(fmaf(acc[7], g2r[7], b2r[7]), 0.0f);
        h1a[pos] = ha; h1b[pos] = hb;
    }
    __syncthreads();

    // phase 3A: inactive outputs = residual copy (disjoint from 3B -> no race)
    for (int i = tid; i < T2; i += 256) {
        int ty = i / TILE, tx = i % TILE;
        int gy = r0 + ty, gx = c0 + tx;
        if (gy < H && gx < H && msh[(ty + 2) * XT + tx + 2] <= 0.0f) {
            const float* rp = in + ((size_t)(b * H + gy) * H + gx) * 8;
            float* op = out + ((size_t)(b * H + gy) * H + gx) * 8;
            *(float4*)op = *(const float4*)rp;
            *(float4*)(op + 4) = *(const float4*)(rp + 4);
        }
    }
    // phase 3B: conv2 at ACTIVE output pixels + residual
    int n3 = cnt3;
    for (int k = tid; k < n3; k += 256) {
        int pos = list3[k];
        int ty = pos / TILE, tx = pos % TILE;
        int gy = r0 + ty, gx = c0 + tx;
        float acc[8];
        #pragma unroll
        for (int co = 0; co < 8; ++co) acc[co] = 0.0f;
        #pragma unroll
        for (int kh = 0; kh < 3; ++kh)
            #pragma unroll
            for (int kw = 0; kw < 3; ++kw) {
                int pix = (ty + kh) * HT + tx + kw;
                float4 a = h1a[pix], c4 = h1b[pix];
                const float* wp = w2 + (kh * 3 + kw) * 64;
                #pragma unroll
                for (int co = 0; co < 8; ++co) {
                    float s = fmaf(a.x,  wp[co],      acc[co]);
                    s = fmaf(a.y,  wp[8  + co], s);
                    s = fmaf(a.z,  wp[16 + co], s);
                    s = fmaf(a.w,  wp[24 + co], s);
                    s = fmaf(c4.x, wp[32 + co], s);
                    s = fmaf(c4.y, wp[40 + co], s);
                    s = fmaf(c4.z, wp[48 + co], s);
                    acc[co] = fmaf(c4.w, wp[56 + co], s);
                }
            }
        const float* rp = in + ((size_t)(b * H + gy) * H + gx) * 8;
        float* op = out + ((size_t)(b * H + gy) * H + gx) * 8;
        float4 ra = *(const float4*)rp;
        float4 rb = *(const float4*)(rp + 4);
        *(float4*)op       = make_float4(acc[0] + ra.x, acc[1] + ra.y, acc[2] + ra.z, acc[3] + ra.w);
        *(float4*)(op + 4) = make_float4(acc[4] + rb.x, acc[5] + rb.y, acc[6] + rb.z, acc[7] + rb.w);
    }
}

// Fused conv: optionally bnrelu on input, conv, * mOut, [+ res].
// Tap-serial form: ~36 VGPR, occupancy-driven latency hiding.
template <int K, int CIN, int COUT, int COT, bool BN, bool RES>
__global__ __launch_bounds__(256) void fconv_kernel(
    const float* __restrict__ in, const float* __restrict__ w,
    const float* __restrict__ g, const float* __restrict__ bbn,
    const float* __restrict__ mIn, const float* __restrict__ mOut,
    const float* __restrict__ res, float* __restrict__ out,
    int Hin, int Hout, int stride, int pad) {
    const int Win = Hin, Wout = Hout;
    int npix = BATCH * Hout * Wout;
    int opix = blockIdx.x * 256 + threadIdx.x;
    if (opix >= npix) return;
    int co0 = blockIdx.y * COT;
    int wo = opix % Wout;
    int t = opix / Wout;
    int ho = t % Hout;
    int b  = t / Hout;

    float mo = mOut[opix];
    float* op = out + (size_t)opix * COUT + co0;
    if (mo <= 0.0f) {
        #pragma unroll
        for (int j = 0; j < COT; j += 4) {
            float4 r4 = RES ? *(const float4*)(res + (size_t)opix * COUT + co0 + j)
                            : make_float4(0,0,0,0);
            *(float4*)(op + j) = r4;
        }
        return;
    }
    float acc[COT];
    #pragma unroll
    for (int j = 0; j < COT; ++j) acc[j] = 0.0f;

    #pragma unroll
    for (int kh = 0; kh < K; ++kh) {
        int ih = ho * stride + kh - pad;
        if ((unsigned)ih >= (unsigned)Hin) continue;
        #pragma unroll
        for (int kw = 0; kw < K; ++kw) {
            int iw = wo * stride + kw - pad;
            if ((unsigned)iw >= (unsigned)Win) continue;
            int ipix = (b * Hin + ih) * Win + iw;
            float mi = 1.0f;
            if (BN) { mi = mIn[ipix]; if (mi <= 0.0f) continue; }
            const float* ip = in + (size_t)ipix * CIN;
            const float* wp = w + (kh * K + kw) * CIN * COUT + co0;
            #pragma unroll
            for (int ci = 0; ci < CIN; ci += 4) {
                float4 xv = *(const float4*)(ip + ci);
                if (BN) {
                    xv.x = mi * fmaxf(fmaf(xv.x, g[ci],     bbn[ci]),     0.0f);
                    xv.y = mi * fmaxf(fmaf(xv.y, g[ci + 1], bbn[ci + 1]), 0.0f);
                    xv.z = mi * fmaxf(fmaf(xv.z, g[ci + 2], bbn[ci + 2]), 0.0f);
                    xv.w = mi * fmaxf(fmaf(xv.w, g[ci + 3], bbn[ci + 3]), 0.0f);
                }
                #pragma unroll
                for (int j = 0; j < COT; ++j) {
                    acc[j] = fmaf(xv.x, wp[(ci    ) * COUT + j], acc[j]);
                    acc[j] = fmaf(xv.y, wp[(ci + 1) * COUT + j], acc[j]);
                    acc[j] = fmaf(xv.z, wp[(ci + 2) * COUT + j], acc[j]);
                    acc[j] = fmaf(xv.w, wp[(ci + 3) * COUT + j], acc[j]);
                }
            }
        }
    }
    #pragma unroll
    for (int j = 0; j < COT; j += 4) {
        float4 o4;
        o4.x = acc[j] * mo; o4.y = acc[j+1] * mo; o4.z = acc[j+2] * mo; o4.w = acc[j+3] * mo;
        if (RES) {
            float4 r4 = *(const float4*)(res + (size_t)opix * COUT + co0 + j);
            o4.x += r4.x; o4.y += r4.y; o4.z += r4.z; o4.w += r4.w;
        }
        *(float4*)(op + j) = o4;
    }
}

// Fused downsample stage, BOTH paths in one pass (input/mask loaded once):
//   m2 = maxpool3x3s2(mIn)  (written by blockIdx.y == 0)
//   outR = conv3x3s2(x) * m2 ; outA = conv3x3s2(bnrelu(x)) * m2
template <int CIN, int COUT, int COT>
__global__ __launch_bounds__(256) void strided_both_kernel(
    const float* __restrict__ in,
    const float* __restrict__ wR, const float* __restrict__ wA,
    const float* __restrict__ g, const float* __restrict__ bbn,
    const float* __restrict__ mIn, float* __restrict__ mOutBuf,
    float* __restrict__ outR, float* __restrict__ outA,
    int Hin, int Hout) {
    int npix = BATCH * Hout * Hout;
    int opix = blockIdx.x * 256 + threadIdx.x;
    if (opix >= npix) return;
    int co0 = blockIdx.y * COT;
    int wo = opix % Hout;
    int t = opix / Hout;
    int ho = t % Hout;
    int b  = t / Hout;

    float accR[COT], accA[COT];
    #pragma unroll
    for (int j = 0; j < COT; ++j) { accR[j] = 0.0f; accA[j] = 0.0f; }
    float m2 = 0.0f;

    #pragma unroll
    for (int kh = 0; kh < 3; ++kh) {
        int ih = 2 * ho + kh;
        #pragma unroll
        for (int kw = 0; kw < 3; ++kw) {
            int iw = 2 * wo + kw;
            int ipix = (b * Hin + ih) * Hin + iw;
            float mi = mIn[ipix];
            if (mi <= 0.0f) continue;
            m2 = fmaxf(m2, mi);
            const float* ip  = in + (size_t)ipix * CIN;
            const float* wpR = wR + (kh * 3 + kw) * CIN * COUT + co0;
            const float* wpA = wA + (kh * 3 + kw) * CIN * COUT + co0;
            #pragma unroll
            for (int ci = 0; ci < CIN; ci += 4) {
                float4 xv = *(const float4*)(ip + ci);
                float4 xa;
                xa.x = mi * fmaxf(fmaf(xv.x, g[ci],     bbn[ci]),     0.0f);
                xa.y = mi * fmaxf(fmaf(xv.y, g[ci + 1], bbn[ci + 1]), 0.0f);
                xa.z = mi * fmaxf(fmaf(xv.z, g[ci + 2], bbn[ci + 2]), 0.0f);
                xa.w = mi * fmaxf(fmaf(xv.w, g[ci + 3], bbn[ci + 3]), 0.0f);
                #pragma unroll
                for (int j = 0; j < COT; ++j) {
                    accR[j] = fmaf(xv.x, wpR[(ci    ) * COUT + j], accR[j]);
                    accR[j] = fmaf(xv.y, wpR[(ci + 1) * COUT + j], accR[j]);
                    accR[j] = fmaf(xv.z, wpR[(ci + 2) * COUT + j], accR[j]);
                    accR[j] = fmaf(xv.w, wpR[(ci + 3) * COUT + j], accR[j]);
                    accA[j] = fmaf(xa.x, wpA[(ci    ) * COUT + j], accA[j]);
                    accA[j] = fmaf(xa.y, wpA[(ci + 1) * COUT + j], accA[j]);
                    accA[j] = fmaf(xa.z, wpA[(ci + 2) * COUT + j], accA[j]);
                    accA[j] = fmaf(xa.w, wpA[(ci + 3) * COUT + j], accA[j]);
                }
            }
        }
    }
    if (blockIdx.y == 0) mOutBuf[opix] = m2;
    float* opR = outR + (size_t)opix * COUT + co0;
    float* opA = outA + (size_t)opix * COUT + co0;
    #pragma unroll
    for (int j = 0; j < COT; j += 4) {
        *(float4*)(opR + j) = make_float4(accR[j] * m2, accR[j+1] * m2, accR[j+2] * m2, accR[j+3] * m2);
        *(float4*)(opA + j) = make_float4(accA[j] * m2, accA[j+1] * m2, accA[j+2] * m2, accA[j+3] * m2);
    }
}

// conv_last: 5x5 VALID conv (12,12,32)->(8,8,64) with bnrelu(g16,b16,m1) fused
// on the input. K-split over kh; partials summed in bn_tr.
__global__ __launch_bounds__(256) void convlast_kernel(
    const float* __restrict__ in,      // (128,12,12,32)
    const float* __restrict__ w,       // (5,5,32,64)
    const float* __restrict__ g, const float* __restrict__ bb,
    const float* __restrict__ mIn,     // (128,12,12)
    float* __restrict__ part) {        // (5,128,8,8,64)
    __shared__ float xs[32 * 97];      // planar [ci][row*12+col], pad to 97
    __shared__ float ws[5 * 32 * 64];  // [kw][ci][co] slice for this kh
    int b   = blockIdx.x;
    int kh  = blockIdx.y;
    int tid = threadIdx.x;
    for (int i = tid; i < 8 * 12 * 32; i += 256) {
        int ci = i & 31;
        int p  = i >> 5;                     // row*12+col, 0..95
        int gpix = (b * 12 + kh + p / 12) * 12 + (p % 12);
        float m = mIn[gpix];
        float v = 0.0f;
        if (m > 0.0f) v = fmaxf(fmaf(in[(size_t)gpix * 32 + ci], g[ci], bb[ci]), 0.0f);
        xs[ci * 97 + p] = v;
    }
    {
        const float4* src = (const float4*)(w + kh * (5 * 32 * 64));
        float4* dst = (float4*)ws;
        for (int i = tid; i < 5 * 32 * 64 / 4; i += 256) dst[i] = src[i];
    }
    __syncthreads();

    int px = tid & 63;            // output pixel (ho*8+wo)
    int cg = tid >> 6;            // co group of 16
    int ho = px >> 3, wo = px & 7;
    float acc[16];
    #pragma unroll
    for (int j = 0; j < 16; ++j) acc[j] = 0.0f;
    #pragma unroll
    for (int kw = 0; kw < 5; ++kw) {
        const float* xp = xs + ho * 12 + wo + kw;
        const float* wp = ws + kw * (32 * 64) + cg * 16;
        #pragma unroll
        for (int ci = 0; ci < 32; ++ci) {
            float xv = xp[ci * 97];
            const float* wr = wp + ci * 64;        // wave-uniform -> LDS broadcast
            #pragma unroll
            for (int j = 0; j < 16; j += 4) {
                float4 w4 = *(const float4*)(wr + j);
                acc[j]     = fmaf(xv, w4.x, acc[j]);
                acc[j + 1] = fmaf(xv, w4.y, acc[j + 1]);
                acc[j + 2] = fmaf(xv, w4.z, acc[j + 2]);
                acc[j + 3] = fmaf(xv, w4.w, acc[j + 3]);
            }
        }
    }
    float* op = part + ((((size_t)kh * BATCH + b) * 64 + px) * 64) + cg * 16;
    #pragma unroll
    for (int j = 0; j < 16; j += 4)
        *(float4*)(op + j) = make_float4(acc[j], acc[j+1], acc[j+2], acc[j+3]);
}

// sum 5 kh-partials + bnrelu(g17,b17,m0) + flatten to NCHW-flat: xt[b][c*64+hw]
__global__ __launch_bounds__(256) void bn_tr_kernel(
    const float* __restrict__ part, const float* __restrict__ m,
    const float* __restrict__ g, const float* __restrict__ bb,
    float* __restrict__ xt) {
    int tid = blockIdx.x * 256 + threadIdx.x;
    if (tid >= BATCH * 4096) return;
    int c = tid & 63, hw = (tid >> 6) & 63, b = tid >> 12;
    float s = 0.0f;
    #pragma unroll
    for (int k = 0; k < 5; ++k)
        s += part[(((size_t)k * BATCH + b) * 64 + hw) * 64 + c];
    float v = m[b * 64 + hw] * fmaxf(fmaf(s, g[c], bb[c]), 0.0f);
    xt[((size_t)b << 12) + c * 64 + hw] = v;
}

__global__ void pool_kernel(const float* __restrict__ in, float* __restrict__ out,
                            int Hin, int Win, int Hout, int Wout, int win, int stride) {
    int tid = blockIdx.x * blockDim.x + threadIdx.x;
    int total = BATCH * Hout * Wout;
    if (tid >= total) return;
    int wo = tid % Wout;
    int p = tid / Wout;
    int ho = p % Hout;
    int b  = p / Hout;
    float mx = 0.0f;
    for (int i = 0; i < win; ++i)
        for (int j = 0; j < win; ++j)
            mx = fmaxf(mx, in[(b * Hin + ho * stride + i) * Win + wo * stride + j]);
    out[tid] = mx;
}

// C[128,100] += xt[128,4096] . wl[100,4096]^T, split-K with atomics.
__global__ __launch_bounds__(256) void linear_gemm_kernel(
    const float* __restrict__ xt, const float* __restrict__ wl,
    float* __restrict__ out) {
    int o = blockIdx.x;
    int half = threadIdx.x >> 7;
    int b = threadIdx.x & 127;
    int k0 = blockIdx.y * 512 + half * 256;
    const float* xp = xt + ((size_t)b << 12) + k0;
    const float* wp = wl + o * 4096 + k0;
    float acc = 0.0f;
    #pragma unroll 16
    for (int k = 0; k < 256; k += 4) {
        float4 xv = *(const float4*)(xp + k);
        float4 wv = *(const float4*)(wp + k);
        acc = fmaf(xv.x, wv.x, acc); acc = fmaf(xv.y, wv.y, acc);
        acc = fmaf(xv.z, wv.z, acc); acc = fmaf(xv.w, wv.w, acc);
    }
    atomicAdd(&out[b * 100 + o], acc);
}

template <int K, int CIN, int COUT, int COT, bool BN, bool RES>
static inline void fconv(hipStream_t s, const float* in, const float* w,
                         const float* g, const float* bbn,
                         const float* mIn, const float* mOut, const float* res,
                         float* out, int Hin, int Hout, int stride, int pad) {
    int npix = BATCH * Hout * Hout;
    dim3 grid((npix + 255) / 256, COUT / COT);
    fconv_kernel<K, CIN, COUT, COT, BN, RES><<<grid, 256, 0, s>>>(
        in, w, g, bbn, mIn, mOut, res, out, Hin, Hout, stride, pad);
}

template <int CIN, int COUT, int COT>
static inline void strided_both(hipStream_t s, const float* in, const float* wR, const float* wA,
                                const float* g, const float* bbn, const float* mIn,
                                float* mOutBuf, float* outR, float* outA, int Hin, int Hout) {
    int npix = BATCH * Hout * Hout;
    dim3 grid((npix + 255) / 256, COUT / COT);
    strided_both_kernel<CIN, COUT, COT><<<grid, 256, 0, s>>>(
        in, wR, wA, g, bbn, mIn, mOutBuf, outR, outA, Hin, Hout);
}

extern "C" void kernel_launch(void* const* d_in, const int* in_sizes, int n_in,
                              void* d_out, int out_size, void* d_ws, size_t ws_size,
                              hipStream_t stream) {
    const int*   loc   = (const int*)d_in[0];
    const int*   bidx  = (const int*)d_in[1];
    const float* feat  = (const float*)d_in[2];
    const float* gamma = (const float*)d_in[3];
    const float* beta  = (const float*)d_in[4];
    const float* Wconv0 = (const float*)d_in[5];
    const float* Wc1a = (const float*)d_in[6];
    const float* Wc1b = (const float*)d_in[7];
    const float* Wc2a = (const float*)d_in[8];
    const float* Wc2b = (const float*)d_in[9];
    const float* Wc3a = (const float*)d_in[10];
    const float* Wc3b = (const float*)d_in[11];
    const float* Wc3r = (const float*)d_in[12];
    const float* Wc4a = (const float*)d_in[13];
    const float* Wc4b = (const float*)d_in[14];
    const float* Wc5a = (const float*)d_in[15];
    const float* Wc5b = (const float*)d_in[16];
    const float* Wc5r = (const float*)d_in[17];
    const float* Wc6a = (const float*)d_in[18];
    const float* Wc6b = (const float*)d_in[19];
    const float* Wc7a = (const float*)d_in[20];
    const float* Wc7b = (const float*)d_in[21];
    const float* Wc7r = (const float*)d_in[22];
    const float* Wc8a = (const float*)d_in[23];
    const float* Wc8b = (const float*)d_in[24];
    const float* Wlast = (const float*)d_in[25];
    const float* wlin  = (const float*)d_in[26];

    const size_t SZB = (size_t)BATCH * 103 * 103 * 8;
    const size_t SZM = (size_t)BATCH * 103 * 103;
    float* b0 = (float*)d_ws;
    float* b1 = b0 + SZB;
    float* b2 = b1 + SZB;
    float* m0 = b2 + SZB;
    float* m1 = m0 + SZM;

    const float* G[18];
    const float* Bt[18];
    for (int i = 0; i < 18; ++i) { G[i] = gamma + OFFS[i]; Bt[i] = beta + OFFS[i]; }

    // scatter into xs(b1), ms(b2)
    {
        int n = BATCH * S * S;
        zero2_kernel<<<(n / 4 + 255) / 256, 256, 0, stream>>>((float4*)b1, (float4*)b2, n / 4);
        scatter_kernel<<<(NPTS + 255) / 256, 256, 0, stream>>>(loc, bidx, feat, b1, b2);
        int total = BATCH * 103 * 103;
        conv0_pool_kernel<<<(total + 255) / 256, 256, 0, stream>>>(b1, b2, Wconv0, b0, m0);
    }
    // x = b0 (103,103,8), mask = m0

    // c1, c2: sparsity-compacted fused residual blocks
    resblock8_kernel<<<dim3(7 * 7 * BATCH), 256, 0, stream>>>(
        b0, m0, Wc1a, Wc1b, G[0], Bt[0], G[1], Bt[1], b1, 103);
    resblock8_kernel<<<dim3(7 * 7 * BATCH), 256, 0, stream>>>(
        b1, m0, Wc2a, Wc2b, G[2], Bt[2], G[3], Bt[3], b2, 103);
    // x = b2
    // c3 (stride2, 103->51, 8->16): both paths fused, input read once
    strided_both<8, 16, 16>(stream, b2, Wc3r, Wc3a, G[4], Bt[4], m0, m1, b0, b1, 103, 51);
    fconv<3, 16, 16, 8, true, true >(stream, b1, Wc3b, G[5], Bt[5], m1, m1, b0, b2, 51, 51, 1, 1);
    // x = b2, mask = m1
    // c4 (fconv pair: resblock regresses at C>=16, round-3 lesson)
    fconv<3, 16, 16, 8, true, false>(stream, b2, Wc4a, G[6], Bt[6], m1, m1, nullptr, b0, 51, 51, 1, 1);
    fconv<3, 16, 16, 8, true, true >(stream, b0, Wc4b, G[7], Bt[7], m1, m1, b2,      b1, 51, 51, 1, 1);
    // x = b1
    // c5 (stride2, 51->25, 16->24): both paths fused, COT=12
    strided_both<16, 24, 12>(stream, b1, Wc5r, Wc5a, G[8], Bt[8], m1, m0, b0, b2, 51, 25);
    fconv<3, 24, 24, 8, true, true >(stream, b2, Wc5b, G[9], Bt[9], m0, m0, b0, b1, 25, 25, 1, 1);
    // x = b1, mask = m0
    // c6 (fconv pair)
    fconv<3, 24, 24, 8, true, false>(stream, b1, Wc6a, G[10], Bt[10], m0, m0, nullptr, b0, 25, 25, 1, 1);
    fconv<3, 24, 24, 8, true, true >(stream, b0, Wc6b, G[11], Bt[11], m0, m0, b1,      b2, 25, 25, 1, 1);
    // x = b2
    // c7 (stride2, 25->12, 24->32): both paths fused, COT=8
    strided_both<24, 32, 8>(stream, b2, Wc7r, Wc7a, G[12], Bt[12], m0, m1, b0, b1, 25, 12);
    fconv<3, 32, 32, 4, true, true >(stream, b1, Wc7b, G[13], Bt[13], m1, m1, b0, b2, 12, 12, 1, 1);
    // x = b2, mask = m1
    // c8
    fconv<3, 32, 32, 4, true, false>(stream, b2, Wc8a, G[14], Bt[14], m1, m1, nullptr, b0, 12, 12, 1, 1);
    fconv<3, 32, 32, 4, true, true >(stream, b0, Wc8b, G[15], Bt[15], m1, m1, b2,      b1, 12, 12, 1, 1);
    // x = b1
    // tail: pooled mask, LDS-tiled conv_last (kh-split partials in b0), fused sum+bn+tr
    pool_kernel<<<(BATCH * 64 + 255) / 256, 256, 0, stream>>>(m1, m0, 12, 12, 8, 8, 5, 1);
    convlast_kernel<<<dim3(BATCH, 5), 256, 0, stream>>>(b1, Wlast, G[16], Bt[16], m1, b0);
    bn_tr_kernel<<<(BATCH * 4096 + 255) / 256, 256, 0, stream>>>(b0, m0, G[17], Bt[17], b2);
    zero_kernel<<<(BATCH * 100 + 255) / 256, 256, 0, stream>>>((float*)d_out, BATCH * 100);
    linear_gemm_kernel<<<dim3(100, 8), 256, 0, stream>>>(b2, wlin, (float*)d_out);
}

// Round 7
// 761.084 us; speedup vs baseline: 1.1820x; 1.1820x over previous
//
#include <hip/hip_runtime.h>

#define S 207
#define BATCH 128
#define NPTS 256000

static const int OFFS[19] = {0,8,16,24,32,40,56,72,88,104,128,152,176,200,232,264,296,328,392};

__global__ void zero2_kernel(float4* __restrict__ a, float4* __restrict__ b, int n4) {
    int i = blockIdx.x * blockDim.x + threadIdx.x;
    if (i < n4) { a[i] = make_float4(0,0,0,0); b[i] = make_float4(0,0,0,0); }
}

__global__ void zero_kernel(float* __restrict__ p, int n) {
    int i = blockIdx.x * blockDim.x + threadIdx.x;
    if (i < n) p[i] = 0.0f;
}

__global__ void scatter_kernel(const int* __restrict__ loc, const int* __restrict__ bidx,
                               const float* __restrict__ feat,
                               float* __restrict__ xs, float* __restrict__ ms) {
    int t = blockIdx.x * blockDim.x + threadIdx.x;
    if (t >= NPTS) return;
    int b = bidx[t];
    int r = loc[2 * t];
    int c = loc[2 * t + 1];
    int idx = (b * S + r) * S + c;
    atomicAdd(&xs[idx], feat[t]);
    ms[idx] = 1.0f;
}

// Fused conv0(SAME)*m -> masked 3x2 maxpool. One thread per output pixel, all 8 channels.
__global__ __launch_bounds__(256) void conv0_pool_kernel(
    const float* __restrict__ xs, const float* __restrict__ ms,
    const float* __restrict__ w,   // (3,3,1,8)
    float* __restrict__ x1, float* __restrict__ m1) {
    const int Hout = 103;
    int opix = blockIdx.x * 256 + threadIdx.x;
    int total = BATCH * Hout * Hout;
    if (opix >= total) return;
    int wo = opix % Hout;
    int t = opix / Hout;
    int ho = t % Hout;
    int b  = t / Hout;

    float mv[3][3];
    float mwin = 0.0f;
    #pragma unroll
    for (int pi = 0; pi < 3; ++pi)
        #pragma unroll
        for (int pj = 0; pj < 3; ++pj) {
            float m = ms[(b * S + 2 * ho + pi) * S + 2 * wo + pj];
            mv[pi][pj] = m;
            mwin = fmaxf(mwin, m);
        }
    float* xp = x1 + (size_t)opix * 8;
    if (mwin <= 0.0f) {
        *(float4*)xp = make_float4(0,0,0,0);
        *(float4*)(xp + 4) = make_float4(0,0,0,0);
        m1[opix] = 0.0f;
        return;
    }
    float p[5][5];
    #pragma unroll
    for (int r = 0; r < 5; ++r) {
        int ii = 2 * ho - 1 + r;
        #pragma unroll
        for (int c = 0; c < 5; ++c) {
            int jj = 2 * wo - 1 + c;
            bool ok = ((unsigned)ii < (unsigned)S) && ((unsigned)jj < (unsigned)S);
            p[r][c] = ok ? xs[(b * S + ii) * S + jj] : 0.0f;
        }
    }
    float best[8];
    #pragma unroll
    for (int co = 0; co < 8; ++co) best[co] = -1e30f;
    #pragma unroll
    for (int pi = 0; pi < 3; ++pi)
        #pragma unroll
        for (int pj = 0; pj < 3; ++pj) {
            if (mv[pi][pj] > 0.0f) {
                float acc[8];
                #pragma unroll
                for (int co = 0; co < 8; ++co) acc[co] = 0.0f;
                #pragma unroll
                for (int kh = 0; kh < 3; ++kh)
                    #pragma unroll
                    for (int kw = 0; kw < 3; ++kw) {
                        float x = p[pi + kh][pj + kw];
                        #pragma unroll
                        for (int co = 0; co < 8; ++co)
                            acc[co] = fmaf(x, w[(kh * 3 + kw) * 8 + co], acc[co]);
                    }
                #pragma unroll
                for (int co = 0; co < 8; ++co) best[co] = fmaxf(best[co], acc[co]);
            }
        }
    *(float4*)xp = make_float4(best[0], best[1], best[2], best[3]);
    *(float4*)(xp + 4) = make_float4(best[4], best[5], best[6], best[7]);
    m1[opix] = 1.0f;
}

// Fused full residual block (stride 1, C=8 only: weight block is 2.3 KB ->
// compiler keeps it scalar-resident). Round-4 version: 40 VGPR, 50% occupancy,
// 58 us/dispatch. Compaction variants regress (rounds 5/6: VGPR 72, occ 26%).
template <int C, int TILE, int NTX>
__global__ __launch_bounds__(256) void resblock_kernel(
    const float* __restrict__ in, const float* __restrict__ mask,
    const float* __restrict__ w1, const float* __restrict__ w2,
    const float* __restrict__ g1, const float* __restrict__ bb1,
    const float* __restrict__ g2, const float* __restrict__ bb2,
    float* __restrict__ out, int H) {
    constexpr int XT = TILE + 4, HT = TILE + 2;
    constexpr int XA = XT * XT, HA = HT * HT;
    __shared__ float xs[C][XA];     // bnrelu1'd input, 2-halo
    __shared__ float h1[C][HA];     // bnrelu2'd intermediate, 1-halo
    __shared__ float msh[XA];

    int tid = threadIdx.x;
    int bid = blockIdx.x;
    int b = bid / (NTX * NTX);
    int t = bid % (NTX * NTX);
    int r0 = (t / NTX) * TILE, c0 = (t % NTX) * TILE;

    float gr[C], br[C];
    #pragma unroll
    for (int c = 0; c < C; ++c) { gr[c] = g1[c]; br[c] = bb1[c]; }

    // phase 1: load + bnrelu1 -> planar LDS (float4 global loads; masked skip)
    for (int i = tid; i < XA; i += 256) {
        int py = i / XT, px = i % XT;
        int gy = r0 - 2 + py, gx = c0 - 2 + px;
        bool ok = (unsigned)gy < (unsigned)H && (unsigned)gx < (unsigned)H;
        float m = 0.0f;
        if (ok) m = mask[(size_t)(b * H + gy) * H + gx];
        msh[i] = m;
        if (m > 0.0f) {
            const float* ip = in + ((size_t)(b * H + gy) * H + gx) * C;
            #pragma unroll
            for (int c = 0; c < C; c += 4) {
                float4 x4 = *(const float4*)(ip + c);
                xs[c    ][i] = m * fmaxf(fmaf(x4.x, gr[c],     br[c]),     0.0f);
                xs[c + 1][i] = m * fmaxf(fmaf(x4.y, gr[c + 1], br[c + 1]), 0.0f);
                xs[c + 2][i] = m * fmaxf(fmaf(x4.z, gr[c + 2], br[c + 2]), 0.0f);
                xs[c + 3][i] = m * fmaxf(fmaf(x4.w, gr[c + 3], br[c + 3]), 0.0f);
            }
        } else {
            #pragma unroll
            for (int c = 0; c < C; ++c) xs[c][i] = 0.0f;
        }
    }
    #pragma unroll
    for (int c = 0; c < C; ++c) { gr[c] = g2[c]; br[c] = bb2[c]; }
    __syncthreads();

    // phase 2: conv1 over the 1-halo region; bnrelu2 fused into the store
    for (int pos = tid; pos < HA; pos += 256) {
        int py = pos / HT, px = pos % HT;
        float mc = msh[(py + 1) * XT + px + 1];
        float acc[C];
        #pragma unroll
        for (int co = 0; co < C; ++co) acc[co] = 0.0f;
        if (mc > 0.0f) {
            #pragma unroll
            for (int kh = 0; kh < 3; ++kh)
                #pragma unroll
                for (int kw = 0; kw < 3; ++kw) {
                    int pix = (py + kh) * XT + px + kw;
                    const float* wp = w1 + (kh * 3 + kw) * C * C;   // wave-uniform -> s_load
                    #pragma unroll
                    for (int ci = 0; ci < C; ++ci) {
                        float xv = xs[ci][pix];
                        #pragma unroll
                        for (int co = 0; co < C; ++co)
                            acc[co] = fmaf(xv, wp[ci * C + co], acc[co]);
                    }
                }
        }
        #pragma unroll
        for (int co = 0; co < C; ++co)
            h1[co][pos] = mc * fmaxf(fmaf(acc[co] * mc, gr[co], br[co]), 0.0f);
    }
    __syncthreads();

    // phase 3: conv2 at the TILE x TILE center + residual (re-read x, L2-hot)
    for (int pos = tid; pos < TILE * TILE; pos += 256) {
        int ty = pos / TILE, tx = pos % TILE;
        int gy = r0 + ty, gx = c0 + tx;
        if (gy < H && gx < H) {
            float mo = msh[(ty + 2) * XT + tx + 2];
            float acc[C];
            #pragma unroll
            for (int co = 0; co < C; ++co) acc[co] = 0.0f;
            if (mo > 0.0f) {
                #pragma unroll
                for (int kh = 0; kh < 3; ++kh)
                    #pragma unroll
                    for (int kw = 0; kw < 3; ++kw) {
                        int pix = (ty + kh) * HT + tx + kw;
                        const float* wp = w2 + (kh * 3 + kw) * C * C;
                        #pragma unroll
                        for (int ci = 0; ci < C; ++ci) {
                            float xv = h1[ci][pix];
                            #pragma unroll
                            for (int co = 0; co < C; ++co)
                                acc[co] = fmaf(xv, wp[ci * C + co], acc[co]);
                        }
                    }
            }
            const float* rp = in + ((size_t)(b * H + gy) * H + gx) * C;
            float* op = out + ((size_t)(b * H + gy) * H + gx) * C;
            #pragma unroll
            for (int j = 0; j < C; j += 4) {
                float4 r4 = *(const float4*)(rp + j);
                float4 o4;
                o4.x = fmaf(acc[j],     mo, r4.x);
                o4.y = fmaf(acc[j + 1], mo, r4.y);
                o4.z = fmaf(acc[j + 2], mo, r4.z);
                o4.w = fmaf(acc[j + 3], mo, r4.w);
                *(float4*)(op + j) = o4;
            }
        }
    }
}

// Dense 3x3 SAME conv, C=16 (51x51 stages where mask is ~98% dense):
// out = conv(bnrelu_masked(in)) * mo [+ res].
// convlast pattern: input tile AND weights staged in LDS; weight reads are
// wave-uniform LDS broadcasts (round-3 lesson: global weights at C>=16
// serialize on s_loads; LDS weights fixed convlast 77 -> ~15 us).
template <bool RES>
__global__ __launch_bounds__(256) void fconv16_lds_kernel(
    const float* __restrict__ in, const float* __restrict__ w,
    const float* __restrict__ g, const float* __restrict__ bbn,
    const float* __restrict__ mask, const float* __restrict__ res,
    float* __restrict__ out, int H, int NTX) {
    constexpr int TILE = 16, XT = TILE + 2;
    constexpr int XA = XT * XT;                // 324
    __shared__ float4 xs[4][XA];               // bnrelu'd input, ch-groups of 4 (20.7 KB)
    __shared__ float  wsh[9 * 16 * 16];        // [tap][ci][co] (9.2 KB)
    __shared__ float  msh[XA];                 // (1.3 KB)

    int tid = threadIdx.x;
    int bid = blockIdx.x;
    int b = bid / (NTX * NTX);
    int t = bid % (NTX * NTX);
    int r0 = (t / NTX) * TILE, c0 = (t % NTX) * TILE;

    // stage weights (576 float4s)
    {
        const float4* src = (const float4*)w;
        float4* dst = (float4*)wsh;
        for (int i = tid; i < 9 * 16 * 16 / 4; i += 256) dst[i] = src[i];
    }
    // stage input: bnrelu (mask binary -> mi*relu == relu when active, 0 else)
    for (int i = tid; i < XA; i += 256) {
        int py = i / XT, px = i % XT;
        int gy = r0 - 1 + py, gx = c0 - 1 + px;
        bool ok = (unsigned)gy < (unsigned)H && (unsigned)gx < (unsigned)H;
        float m = ok ? mask[(size_t)(b * H + gy) * H + gx] : 0.0f;
        msh[i] = m;
        float4 v0 = make_float4(0,0,0,0), v1 = v0, v2 = v0, v3 = v0;
        if (m > 0.0f) {
            const float* ip = in + ((size_t)(b * H + gy) * H + gx) * 16;
            float4 x0 = *(const float4*)(ip);
            float4 x1 = *(const float4*)(ip + 4);
            float4 x2 = *(const float4*)(ip + 8);
            float4 x3 = *(const float4*)(ip + 12);
            v0.x = fmaxf(fmaf(x0.x, g[0],  bbn[0]),  0.0f);
            v0.y = fmaxf(fmaf(x0.y, g[1],  bbn[1]),  0.0f);
            v0.z = fmaxf(fmaf(x0.z, g[2],  bbn[2]),  0.0f);
            v0.w = fmaxf(fmaf(x0.w, g[3],  bbn[3]),  0.0f);
            v1.x = fmaxf(fmaf(x1.x, g[4],  bbn[4]),  0.0f);
            v1.y = fmaxf(fmaf(x1.y, g[5],  bbn[5]),  0.0f);
            v1.z = fmaxf(fmaf(x1.z, g[6],  bbn[6]),  0.0f);
            v1.w = fmaxf(fmaf(x1.w, g[7],  bbn[7]),  0.0f);
            v2.x = fmaxf(fmaf(x2.x, g[8],  bbn[8]),  0.0f);
            v2.y = fmaxf(fmaf(x2.y, g[9],  bbn[9]),  0.0f);
            v2.z = fmaxf(fmaf(x2.z, g[10], bbn[10]), 0.0f);
            v2.w = fmaxf(fmaf(x2.w, g[11], bbn[11]), 0.0f);
            v3.x = fmaxf(fmaf(x3.x, g[12], bbn[12]), 0.0f);
            v3.y = fmaxf(fmaf(x3.y, g[13], bbn[13]), 0.0f);
            v3.z = fmaxf(fmaf(x3.z, g[14], bbn[14]), 0.0f);
            v3.w = fmaxf(fmaf(x3.w, g[15], bbn[15]), 0.0f);
        }
        xs[0][i] = v0; xs[1][i] = v1; xs[2][i] = v2; xs[3][i] = v3;
    }
    __syncthreads();

    int ty = tid >> 4, tx = tid & 15;
    int gy = r0 + ty, gx = c0 + tx;
    if (gy >= H || gx >= H) return;   // no barriers after this point
    size_t opix = (size_t)(b * H + gy) * H + gx;
    float mo = msh[(ty + 1) * XT + tx + 1];
    float* op = out + opix * 16;
    if (mo <= 0.0f) {
        #pragma unroll
        for (int j = 0; j < 16; j += 4) {
            float4 r4 = RES ? *(const float4*)(res + opix * 16 + j) : make_float4(0,0,0,0);
            *(float4*)(op + j) = r4;
        }
        return;
    }
    float acc[16];
    #pragma unroll
    for (int j = 0; j < 16; ++j) acc[j] = 0.0f;
    #pragma unroll
    for (int kh = 0; kh < 3; ++kh)
        #pragma unroll
        for (int kw = 0; kw < 3; ++kw) {
            int pix = (ty + kh) * XT + tx + kw;
            const float* wp = wsh + (kh * 3 + kw) * 256;
            #pragma unroll
            for (int q = 0; q < 4; ++q) {
                float4 xv = xs[q][pix];                 // stride-1 per lane, conflict-free
                const float* wr = wp + q * 64;          // uniform -> broadcast
                #pragma unroll
                for (int j = 0; j < 16; j += 4) {
                    float4 wa = *(const float4*)(wr + j);
                    float4 wb = *(const float4*)(wr + 16 + j);
                    float4 wc = *(const float4*)(wr + 32 + j);
                    float4 wd = *(const float4*)(wr + 48 + j);
                    acc[j]     = fmaf(xv.x, wa.x, acc[j]);
                    acc[j + 1] = fmaf(xv.x, wa.y, acc[j + 1]);
                    acc[j + 2] = fmaf(xv.x, wa.z, acc[j + 2]);
                    acc[j + 3] = fmaf(xv.x, wa.w, acc[j + 3]);
                    acc[j]     = fmaf(xv.y, wb.x, acc[j]);
                    acc[j + 1] = fmaf(xv.y, wb.y, acc[j + 1]);
                    acc[j + 2] = fmaf(xv.y, wb.z, acc[j + 2]);
                    acc[j + 3] = fmaf(xv.y, wb.w, acc[j + 3]);
                    acc[j]     = fmaf(xv.z, wc.x, acc[j]);
                    acc[j + 1] = fmaf(xv.z, wc.y, acc[j + 1]);
                    acc[j + 2] = fmaf(xv.z, wc.z, acc[j + 2]);
                    acc[j + 3] = fmaf(xv.z, wc.w, acc[j + 3]);
                    acc[j]     = fmaf(xv.w, wd.x, acc[j]);
                    acc[j + 1] = fmaf(xv.w, wd.y, acc[j + 1]);
                    acc[j + 2] = fmaf(xv.w, wd.z, acc[j + 2]);
                    acc[j + 3] = fmaf(xv.w, wd.w, acc[j + 3]);
                }
            }
        }
    #pragma unroll
    for (int j = 0; j < 16; j += 4) {
        float4 o4;
        o4.x = acc[j] * mo; o4.y = acc[j+1] * mo; o4.z = acc[j+2] * mo; o4.w = acc[j+3] * mo;
        if (RES) {
            float4 r4 = *(const float4*)(res + opix * 16 + j);
            o4.x += r4.x; o4.y += r4.y; o4.z += r4.z; o4.w += r4.w;
        }
        *(float4*)(op + j) = o4;
    }
}

// Fused conv: optionally bnrelu on input, conv, * mOut, [+ res].
// Tap-serial form: ~36 VGPR, occupancy-driven latency hiding.
template <int K, int CIN, int COUT, int COT, bool BN, bool RES>
__global__ __launch_bounds__(256) void fconv_kernel(
    const float* __restrict__ in, const float* __restrict__ w,
    const float* __restrict__ g, const float* __restrict__ bbn,
    const float* __restrict__ mIn, const float* __restrict__ mOut,
    const float* __restrict__ res, float* __restrict__ out,
    int Hin, int Hout, int stride, int pad) {
    const int Win = Hin, Wout = Hout;
    int npix = BATCH * Hout * Wout;
    int opix = blockIdx.x * 256 + threadIdx.x;
    if (opix >= npix) return;
    int co0 = blockIdx.y * COT;
    int wo = opix % Wout;
    int t = opix / Wout;
    int ho = t % Hout;
    int b  = t / Hout;

    float mo = mOut[opix];
    float* op = out + (size_t)opix * COUT + co0;
    if (mo <= 0.0f) {
        #pragma unroll
        for (int j = 0; j < COT; j += 4) {
            float4 r4 = RES ? *(const float4*)(res + (size_t)opix * COUT + co0 + j)
                            : make_float4(0,0,0,0);
            *(float4*)(op + j) = r4;
        }
        return;
    }
    float acc[COT];
    #pragma unroll
    for (int j = 0; j < COT; ++j) acc[j] = 0.0f;

    #pragma unroll
    for (int kh = 0; kh < K; ++kh) {
        int ih = ho * stride + kh - pad;
        if ((unsigned)ih >= (unsigned)Hin) continue;
        #pragma unroll
        for (int kw = 0; kw < K; ++kw) {
            int iw = wo * stride + kw - pad;
            if ((unsigned)iw >= (unsigned)Win) continue;
            int ipix = (b * Hin + ih) * Win + iw;
            float mi = 1.0f;
            if (BN) { mi = mIn[ipix]; if (mi <= 0.0f) continue; }
            const float* ip = in + (size_t)ipix * CIN;
            const float* wp = w + (kh * K + kw) * CIN * COUT + co0;
            #pragma unroll
            for (int ci = 0; ci < CIN; ci += 4) {
                float4 xv = *(const float4*)(ip + ci);
                if (BN) {
                    xv.x = mi * fmaxf(fmaf(xv.x, g[ci],     bbn[ci]),     0.0f);
                    xv.y = mi * fmaxf(fmaf(xv.y, g[ci + 1], bbn[ci + 1]), 0.0f);
                    xv.z = mi * fmaxf(fmaf(xv.z, g[ci + 2], bbn[ci + 2]), 0.0f);
                    xv.w = mi * fmaxf(fmaf(xv.w, g[ci + 3], bbn[ci + 3]), 0.0f);
                }
                #pragma unroll
                for (int j = 0; j < COT; ++j) {
                    acc[j] = fmaf(xv.x, wp[(ci    ) * COUT + j], acc[j]);
                    acc[j] = fmaf(xv.y, wp[(ci + 1) * COUT + j], acc[j]);
                    acc[j] = fmaf(xv.z, wp[(ci + 2) * COUT + j], acc[j]);
                    acc[j] = fmaf(xv.w, wp[(ci + 3) * COUT + j], acc[j]);
                }
            }
        }
    }
    #pragma unroll
    for (int j = 0; j < COT; j += 4) {
        float4 o4;
        o4.x = acc[j] * mo; o4.y = acc[j+1] * mo; o4.z = acc[j+2] * mo; o4.w = acc[j+3] * mo;
        if (RES) {
            float4 r4 = *(const float4*)(res + (size_t)opix * COUT + co0 + j);
            o4.x += r4.x; o4.y += r4.y; o4.z += r4.z; o4.w += r4.w;
        }
        *(float4*)(op + j) = o4;
    }
}

// Fused downsample stage, BOTH paths in one pass (input/mask loaded once):
//   m2 = maxpool3x3s2(mIn)  (written by blockIdx.y == 0)
//   outR = conv3x3s2(x) * m2 ; outA = conv3x3s2(bnrelu(x)) * m2
template <int CIN, int COUT, int COT>
__global__ __launch_bounds__(256) void strided_both_kernel(
    const float* __restrict__ in,
    const float* __restrict__ wR, const float* __restrict__ wA,
    const float* __restrict__ g, const float* __restrict__ bbn,
    const float* __restrict__ mIn, float* __restrict__ mOutBuf,
    float* __restrict__ outR, float* __restrict__ outA,
    int Hin, int Hout) {
    int npix = BATCH * Hout * Hout;
    int opix = blockIdx.x * 256 + threadIdx.x;
    if (opix >= npix) return;
    int co0 = blockIdx.y * COT;
    int wo = opix % Hout;
    int t = opix / Hout;
    int ho = t % Hout;
    int b  = t / Hout;

    float accR[COT], accA[COT];
    #pragma unroll
    for (int j = 0; j < COT; ++j) { accR[j] = 0.0f; accA[j] = 0.0f; }
    float m2 = 0.0f;

    #pragma unroll
    for (int kh = 0; kh < 3; ++kh) {
        int ih = 2 * ho + kh;
        #pragma unroll
        for (int kw = 0; kw < 3; ++kw) {
            int iw = 2 * wo + kw;
            int ipix = (b * Hin + ih) * Hin + iw;
            float mi = mIn[ipix];
            if (mi <= 0.0f) continue;
            m2 = fmaxf(m2, mi);
            const float* ip  = in + (size_t)ipix * CIN;
            const float* wpR = wR + (kh * 3 + kw) * CIN * COUT + co0;
            const float* wpA = wA + (kh * 3 + kw) * CIN * COUT + co0;
            #pragma unroll
            for (int ci = 0; ci < CIN; ci += 4) {
                float4 xv = *(const float4*)(ip + ci);
                float4 xa;
                xa.x = mi * fmaxf(fmaf(xv.x, g[ci],     bbn[ci]),     0.0f);
                xa.y = mi * fmaxf(fmaf(xv.y, g[ci + 1], bbn[ci + 1]), 0.0f);
                xa.z = mi * fmaxf(fmaf(xv.z, g[ci + 2], bbn[ci + 2]), 0.0f);
                xa.w = mi * fmaxf(fmaf(xv.w, g[ci + 3], bbn[ci + 3]), 0.0f);
                #pragma unroll
                for (int j = 0; j < COT; ++j) {
                    accR[j] = fmaf(xv.x, wpR[(ci    ) * COUT + j], accR[j]);
                    accR[j] = fmaf(xv.y, wpR[(ci + 1) * COUT + j], accR[j]);
                    accR[j] = fmaf(xv.z, wpR[(ci + 2) * COUT + j], accR[j]);
                    accR[j] = fmaf(xv.w, wpR[(ci + 3) * COUT + j], accR[j]);
                    accA[j] = fmaf(xa.x, wpA[(ci    ) * COUT + j], accA[j]);
                    accA[j] = fmaf(xa.y, wpA[(ci + 1) * COUT + j], accA[j]);
                    accA[j] = fmaf(xa.z, wpA[(ci + 2) * COUT + j], accA[j]);
                    accA[j] = fmaf(xa.w, wpA[(ci + 3) * COUT + j], accA[j]);
                }
            }
        }
    }
    if (blockIdx.y == 0) mOutBuf[opix] = m2;
    float* opR = outR + (size_t)opix * COUT + co0;
    float* opA = outA + (size_t)opix * COUT + co0;
    #pragma unroll
    for (int j = 0; j < COT; j += 4) {
        *(float4*)(opR + j) = make_float4(accR[j] * m2, accR[j+1] * m2, accR[j+2] * m2, accR[j+3] * m2);
        *(float4*)(opA + j) = make_float4(accA[j] * m2, accA[j+1] * m2, accA[j+2] * m2, accA[j+3] * m2);
    }
}

// conv_last: 5x5 VALID conv (12,12,32)->(8,8,64) with bnrelu(g16,b16,m1) fused
// on the input. K-split over kh; partials summed in bn_tr.
__global__ __launch_bounds__(256) void convlast_kernel(
    const float* __restrict__ in,      // (128,12,12,32)
    const float* __restrict__ w,       // (5,5,32,64)
    const float* __restrict__ g, const float* __restrict__ bb,
    const float* __restrict__ mIn,     // (128,12,12)
    float* __restrict__ part) {        // (5,128,8,8,64)
    __shared__ float xs[32 * 97];      // planar [ci][row*12+col], pad to 97
    __shared__ float ws[5 * 32 * 64];  // [kw][ci][co] slice for this kh
    int b   = blockIdx.x;
    int kh  = blockIdx.y;
    int tid = threadIdx.x;
    for (int i = tid; i < 8 * 12 * 32; i += 256) {
        int ci = i & 31;
        int p  = i >> 5;                     // row*12+col, 0..95
        int gpix = (b * 12 + kh + p / 12) * 12 + (p % 12);
        float m = mIn[gpix];
        float v = 0.0f;
        if (m > 0.0f) v = fmaxf(fmaf(in[(size_t)gpix * 32 + ci], g[ci], bb[ci]), 0.0f);
        xs[ci * 97 + p] = v;
    }
    {
        const float4* src = (const float4*)(w + kh * (5 * 32 * 64));
        float4* dst = (float4*)ws;
        for (int i = tid; i < 5 * 32 * 64 / 4; i += 256) dst[i] = src[i];
    }
    __syncthreads();

    int px = tid & 63;            // output pixel (ho*8+wo)
    int cg = tid >> 6;            // co group of 16
    int ho = px >> 3, wo = px & 7;
    float acc[16];
    #pragma unroll
    for (int j = 0; j < 16; ++j) acc[j] = 0.0f;
    #pragma unroll
    for (int kw = 0; kw < 5; ++kw) {
        const float* xp = xs + ho * 12 + wo + kw;
        const float* wp = ws + kw * (32 * 64) + cg * 16;
        #pragma unroll
        for (int ci = 0; ci < 32; ++ci) {
            float xv = xp[ci * 97];
            const float* wr = wp + ci * 64;        // wave-uniform -> LDS broadcast
            #pragma unroll
            for (int j = 0; j < 16; j += 4) {
                float4 w4 = *(const float4*)(wr + j);
                acc[j]     = fmaf(xv, w4.x, acc[j]);
                acc[j + 1] = fmaf(xv, w4.y, acc[j + 1]);
                acc[j + 2] = fmaf(xv, w4.z, acc[j + 2]);
                acc[j + 3] = fmaf(xv, w4.w, acc[j + 3]);
            }
        }
    }
    float* op = part + ((((size_t)kh * BATCH + b) * 64 + px) * 64) + cg * 16;
    #pragma unroll
    for (int j = 0; j < 16; j += 4)
        *(float4*)(op + j) = make_float4(acc[j], acc[j+1], acc[j+2], acc[j+3]);
}

// sum 5 kh-partials + bnrelu(g17,b17,m0) + flatten to NCHW-flat: xt[b][c*64+hw]
__global__ __launch_bounds__(256) void bn_tr_kernel(
    const float* __restrict__ part, const float* __restrict__ m,
    const float* __restrict__ g, const float* __restrict__ bb,
    float* __restrict__ xt) {
    int tid = blockIdx.x * 256 + threadIdx.x;
    if (tid >= BATCH * 4096) return;
    int c = tid & 63, hw = (tid >> 6) & 63, b = tid >> 12;
    float s = 0.0f;
    #pragma unroll
    for (int k = 0; k < 5; ++k)
        s += part[(((size_t)k * BATCH + b) * 64 + hw) * 64 + c];
    float v = m[b * 64 + hw] * fmaxf(fmaf(s, g[c], bb[c]), 0.0f);
    xt[((size_t)b << 12) + c * 64 + hw] = v;
}

__global__ void pool_kernel(const float* __restrict__ in, float* __restrict__ out,
                            int Hin, int Win, int Hout, int Wout, int win, int stride) {
    int tid = blockIdx.x * blockDim.x + threadIdx.x;
    int total = BATCH * Hout * Wout;
    if (tid >= total) return;
    int wo = tid % Wout;
    int p = tid / Wout;
    int ho = p % Hout;
    int b  = p / Hout;
    float mx = 0.0f;
    for (int i = 0; i < win; ++i)
        for (int j = 0; j < win; ++j)
            mx = fmaxf(mx, in[(b * Hin + ho * stride + i) * Win + wo * stride + j]);
    out[tid] = mx;
}

// C[128,100] += xt[128,4096] . wl[100,4096]^T, split-K with atomics.
__global__ __launch_bounds__(256) void linear_gemm_kernel(
    const float* __restrict__ xt, const float* __restrict__ wl,
    float* __restrict__ out) {
    int o = blockIdx.x;
    int half = threadIdx.x >> 7;
    int b = threadIdx.x & 127;
    int k0 = blockIdx.y * 512 + half * 256;
    const float* xp = xt + ((size_t)b << 12) + k0;
    const float* wp = wl + o * 4096 + k0;
    float acc = 0.0f;
    #pragma unroll 16
    for (int k = 0; k < 256; k += 4) {
        float4 xv = *(const float4*)(xp + k);
        float4 wv = *(const float4*)(wp + k);
        acc = fmaf(xv.x, wv.x, acc); acc = fmaf(xv.y, wv.y, acc);
        acc = fmaf(xv.z, wv.z, acc); acc = fmaf(xv.w, wv.w, acc);
    }
    atomicAdd(&out[b * 100 + o], acc);
}

template <int K, int CIN, int COUT, int COT, bool BN, bool RES>
static inline void fconv(hipStream_t s, const float* in, const float* w,
                         const float* g, const float* bbn,
                         const float* mIn, const float* mOut, const float* res,
                         float* out, int Hin, int Hout, int stride, int pad) {
    int npix = BATCH * Hout * Hout;
    dim3 grid((npix + 255) / 256, COUT / COT);
    fconv_kernel<K, CIN, COUT, COT, BN, RES><<<grid, 256, 0, s>>>(
        in, w, g, bbn, mIn, mOut, res, out, Hin, Hout, stride, pad);
}

template <int CIN, int COUT, int COT>
static inline void strided_both(hipStream_t s, const float* in, const float* wR, const float* wA,
                                const float* g, const float* bbn, const float* mIn,
                                float* mOutBuf, float* outR, float* outA, int Hin, int Hout) {
    int npix = BATCH * Hout * Hout;
    dim3 grid((npix + 255) / 256, COUT / COT);
    strided_both_kernel<CIN, COUT, COT><<<grid, 256, 0, s>>>(
        in, wR, wA, g, bbn, mIn, mOutBuf, outR, outA, Hin, Hout);
}

extern "C" void kernel_launch(void* const* d_in, const int* in_sizes, int n_in,
                              void* d_out, int out_size, void* d_ws, size_t ws_size,
                              hipStream_t stream) {
    const int*   loc   = (const int*)d_in[0];
    const int*   bidx  = (const int*)d_in[1];
    const float* feat  = (const float*)d_in[2];
    const float* gamma = (const float*)d_in[3];
    const float* beta  = (const float*)d_in[4];
    const float* Wconv0 = (const float*)d_in[5];
    const float* Wc1a = (const float*)d_in[6];
    const float* Wc1b = (const float*)d_in[7];
    const float* Wc2a = (const float*)d_in[8];
    const float* Wc2b = (const float*)d_in[9];
    const float* Wc3a = (const float*)d_in[10];
    const float* Wc3b = (const float*)d_in[11];
    const float* Wc3r = (const float*)d_in[12];
    const float* Wc4a = (const float*)d_in[13];
    const float* Wc4b = (const float*)d_in[14];
    const float* Wc5a = (const float*)d_in[15];
    const float* Wc5b = (const float*)d_in[16];
    const float* Wc5r = (const float*)d_in[17];
    const float* Wc6a = (const float*)d_in[18];
    const float* Wc6b = (const float*)d_in[19];
    const float* Wc7a = (const float*)d_in[20];
    const float* Wc7b = (const float*)d_in[21];
    const float* Wc7r = (const float*)d_in[22];
    const float* Wc8a = (const float*)d_in[23];
    const float* Wc8b = (const float*)d_in[24];
    const float* Wlast = (const float*)d_in[25];
    const float* wlin  = (const float*)d_in[26];

    const size_t SZB = (size_t)BATCH * 103 * 103 * 8;
    const size_t SZM = (size_t)BATCH * 103 * 103;
    float* b0 = (float*)d_ws;
    float* b1 = b0 + SZB;
    float* b2 = b1 + SZB;
    float* m0 = b2 + SZB;
    float* m1 = m0 + SZM;

    const float* G[18];
    const float* Bt[18];
    for (int i = 0; i < 18; ++i) { G[i] = gamma + OFFS[i]; Bt[i] = beta + OFFS[i]; }

    // scatter into xs(b1), ms(b2)
    {
        int n = BATCH * S * S;
        zero2_kernel<<<(n / 4 + 255) / 256, 256, 0, stream>>>((float4*)b1, (float4*)b2, n / 4);
        scatter_kernel<<<(NPTS + 255) / 256, 256, 0, stream>>>(loc, bidx, feat, b1, b2);
        int total = BATCH * 103 * 103;
        conv0_pool_kernel<<<(total + 255) / 256, 256, 0, stream>>>(b1, b2, Wconv0, b0, m0);
    }
    // x = b0 (103,103,8), mask = m0

    // c1, c2: fused residual blocks (round-4 form, best known)
    resblock_kernel<8, 16, 7><<<dim3(7 * 7 * BATCH), 256, 0, stream>>>(
        b0, m0, Wc1a, Wc1b, G[0], Bt[0], G[1], Bt[1], b1, 103);
    resblock_kernel<8, 16, 7><<<dim3(7 * 7 * BATCH), 256, 0, stream>>>(
        b1, m0, Wc2a, Wc2b, G[2], Bt[2], G[3], Bt[3], b2, 103);
    // x = b2
    // c3 (stride2, 103->51, 8->16): both paths fused, input read once
    strided_both<8, 16, 16>(stream, b2, Wc3r, Wc3a, G[4], Bt[4], m0, m1, b0, b1, 103, 51);
    fconv16_lds_kernel<true><<<dim3(16 * BATCH), 256, 0, stream>>>(
        b1, Wc3b, G[5], Bt[5], m1, b0, b2, 51, 4);
    // x = b2, mask = m1
    // c4: LDS-staged dense convs (mask ~98% dense at 51x51)
    fconv16_lds_kernel<false><<<dim3(16 * BATCH), 256, 0, stream>>>(
        b2, Wc4a, G[6], Bt[6], m1, nullptr, b0, 51, 4);
    fconv16_lds_kernel<true><<<dim3(16 * BATCH), 256, 0, stream>>>(
        b0, Wc4b, G[7], Bt[7], m1, b2, b1, 51, 4);
    // x = b1
    // c5 (stride2, 51->25, 16->24): both paths fused, COT=12
    strided_both<16, 24, 12>(stream, b1, Wc5r, Wc5a, G[8], Bt[8], m1, m0, b0, b2, 51, 25);
    fconv<3, 24, 24, 8, true, true >(stream, b2, Wc5b, G[9], Bt[9], m0, m0, b0, b1, 25, 25, 1, 1);
    // x = b1, mask = m0
    // c6 (fconv pair)
    fconv<3, 24, 24, 8, true, false>(stream, b1, Wc6a, G[10], Bt[10], m0, m0, nullptr, b0, 25, 25, 1, 1);
    fconv<3, 24, 24, 8, true, true >(stream, b0, Wc6b, G[11], Bt[11], m0, m0, b1,      b2, 25, 25, 1, 1);
    // x = b2
    // c7 (stride2, 25->12, 24->32): both paths fused, COT=8
    strided_both<24, 32, 8>(stream, b2, Wc7r, Wc7a, G[12], Bt[12], m0, m1, b0, b1, 25, 12);
    fconv<3, 32, 32, 4, true, true >(stream, b1, Wc7b, G[13], Bt[13], m1, m1, b0, b2, 12, 12, 1, 1);
    // x = b2, mask = m1
    // c8
    fconv<3, 32, 32, 4, true, false>(stream, b2, Wc8a, G[14], Bt[14], m1, m1, nullptr, b0, 12, 12, 1, 1);
    fconv<3, 32, 32, 4, true, true >(stream, b0, Wc8b, G[15], Bt[15], m1, m1, b2,      b1, 12, 12, 1, 1);
    // x = b1
    // tail: pooled mask, LDS-tiled conv_last (kh-split partials in b0), fused sum+bn+tr
    pool_kernel<<<(BATCH * 64 + 255) / 256, 256, 0, stream>>>(m1, m0, 12, 12, 8, 8, 5, 1);
    convlast_kernel<<<dim3(BATCH, 5), 256, 0, stream>>>(b1, Wlast, G[16], Bt[16], m1, b0);
    bn_tr_kernel<<<(BATCH * 4096 + 255) / 256, 256, 0, stream>>>(b0, m0, G[17], Bt[17], b2);
    zero_kernel<<<(BATCH * 100 + 255) / 256, 256, 0, stream>>>((float*)d_out, BATCH * 100);
    linear_gemm_kernel<<<dim3(100, 8), 256, 0, stream>>>(b2, wlin, (float*)d_out);
}

// Round 9
// 738.350 us; speedup vs baseline: 1.2184x; 1.0308x over previous
//
#include <hip/hip_runtime.h>

#define S 207
#define BATCH 128
#define NPTS 256000

static const int OFFS[19] = {0,8,16,24,32,40,56,72,88,104,128,152,176,200,232,264,296,328,392};

__global__ void zero2_kernel(float4* __restrict__ a, float4* __restrict__ b, int n4) {
    int i = blockIdx.x * blockDim.x + threadIdx.x;
    if (i < n4) { a[i] = make_float4(0,0,0,0); b[i] = make_float4(0,0,0,0); }
}

__global__ void zero_kernel(float* __restrict__ p, int n) {
    int i = blockIdx.x * blockDim.x + threadIdx.x;
    if (i < n) p[i] = 0.0f;
}

__global__ void scatter_kernel(const int* __restrict__ loc, const int* __restrict__ bidx,
                               const float* __restrict__ feat,
                               float* __restrict__ xs, float* __restrict__ ms) {
    int t = blockIdx.x * blockDim.x + threadIdx.x;
    if (t >= NPTS) return;
    int b = bidx[t];
    int r = loc[2 * t];
    int c = loc[2 * t + 1];
    int idx = (b * S + r) * S + c;
    atomicAdd(&xs[idx], feat[t]);
    ms[idx] = 1.0f;
}

// Fused conv0(SAME)*m -> masked 3x2 maxpool. One thread per output pixel, all 8 channels.
__global__ __launch_bounds__(256) void conv0_pool_kernel(
    const float* __restrict__ xs, const float* __restrict__ ms,
    const float* __restrict__ w,   // (3,3,1,8)
    float* __restrict__ x1, float* __restrict__ m1) {
    const int Hout = 103;
    int opix = blockIdx.x * 256 + threadIdx.x;
    int total = BATCH * Hout * Hout;
    if (opix >= total) return;
    int wo = opix % Hout;
    int t = opix / Hout;
    int ho = t % Hout;
    int b  = t / Hout;

    float mv[3][3];
    float mwin = 0.0f;
    #pragma unroll
    for (int pi = 0; pi < 3; ++pi)
        #pragma unroll
        for (int pj = 0; pj < 3; ++pj) {
            float m = ms[(b * S + 2 * ho + pi) * S + 2 * wo + pj];
            mv[pi][pj] = m;
            mwin = fmaxf(mwin, m);
        }
    float* xp = x1 + (size_t)opix * 8;
    if (mwin <= 0.0f) {
        *(float4*)xp = make_float4(0,0,0,0);
        *(float4*)(xp + 4) = make_float4(0,0,0,0);
        m1[opix] = 0.0f;
        return;
    }
    float p[5][5];
    #pragma unroll
    for (int r = 0; r < 5; ++r) {
        int ii = 2 * ho - 1 + r;
        #pragma unroll
        for (int c = 0; c < 5; ++c) {
            int jj = 2 * wo - 1 + c;
            bool ok = ((unsigned)ii < (unsigned)S) && ((unsigned)jj < (unsigned)S);
            p[r][c] = ok ? xs[(b * S + ii) * S + jj] : 0.0f;
        }
    }
    float best[8];
    #pragma unroll
    for (int co = 0; co < 8; ++co) best[co] = -1e30f;
    #pragma unroll
    for (int pi = 0; pi < 3; ++pi)
        #pragma unroll
        for (int pj = 0; pj < 3; ++pj) {
            if (mv[pi][pj] > 0.0f) {
                float acc[8];
                #pragma unroll
                for (int co = 0; co < 8; ++co) acc[co] = 0.0f;
                #pragma unroll
                for (int kh = 0; kh < 3; ++kh)
                    #pragma unroll
                    for (int kw = 0; kw < 3; ++kw) {
                        float x = p[pi + kh][pj + kw];
                        #pragma unroll
                        for (int co = 0; co < 8; ++co)
                            acc[co] = fmaf(x, w[(kh * 3 + kw) * 8 + co], acc[co]);
                    }
                #pragma unroll
                for (int co = 0; co < 8; ++co) best[co] = fmaxf(best[co], acc[co]);
            }
        }
    *(float4*)xp = make_float4(best[0], best[1], best[2], best[3]);
    *(float4*)(xp + 4) = make_float4(best[4], best[5], best[6], best[7]);
    m1[opix] = 1.0f;
}

// Fused full residual block, C=8, float4-planar LDS (ds_read_b128: 18 reads/px
// vs 72 b32 in the round-4 form). NO compaction (rounds 5/6 lesson). All LDS
// accesses audited in-bounds; structure identical to the passing round-4/round-6
// kernels. s_load-resident weights (2.3 KB/conv at C=8).
template <int TILE, int NTX>
__global__ __launch_bounds__(256) void resblock8f4_kernel(
    const float* __restrict__ in, const float* __restrict__ mask,
    const float* __restrict__ w1, const float* __restrict__ w2,
    const float* __restrict__ g1, const float* __restrict__ bb1,
    const float* __restrict__ g2, const float* __restrict__ bb2,
    float* __restrict__ out, int H) {
    constexpr int XT = TILE + 4, HT = TILE + 2;
    constexpr int XA = XT * XT, HA = HT * HT;
    __shared__ float4 xsa[XA], xsb[XA];   // bnrelu1'd input (ch0-3, ch4-7), 2-halo
    __shared__ float4 h1a[HA], h1b[HA];   // bnrelu2'd intermediate, 1-halo
    __shared__ float msh[XA];

    int tid = threadIdx.x;
    int bid = blockIdx.x;
    int b = bid / (NTX * NTX);
    int t = bid % (NTX * NTX);
    int r0 = (t / NTX) * TILE, c0 = (t % NTX) * TILE;

    float gr[8], br[8];
    #pragma unroll
    for (int c = 0; c < 8; ++c) { gr[c] = g1[c]; br[c] = bb1[c]; }

    // phase 1: load + bnrelu1 -> float4-planar LDS
    for (int i = tid; i < XA; i += 256) {
        int py = i / XT, px = i % XT;
        int gy = r0 - 2 + py, gx = c0 - 2 + px;
        bool ok = (unsigned)gy < (unsigned)H && (unsigned)gx < (unsigned)H;
        float m = 0.0f;
        if (ok) m = mask[(size_t)(b * H + gy) * H + gx];
        msh[i] = m;
        float4 va = make_float4(0,0,0,0), vb = make_float4(0,0,0,0);
        if (m > 0.0f) {
            const float* ip = in + ((size_t)(b * H + gy) * H + gx) * 8;
            float4 x0 = *(const float4*)ip;
            float4 x1 = *(const float4*)(ip + 4);
            va.x = m * fmaxf(fmaf(x0.x, gr[0], br[0]), 0.0f);
            va.y = m * fmaxf(fmaf(x0.y, gr[1], br[1]), 0.0f);
            va.z = m * fmaxf(fmaf(x0.z, gr[2], br[2]), 0.0f);
            va.w = m * fmaxf(fmaf(x0.w, gr[3], br[3]), 0.0f);
            vb.x = m * fmaxf(fmaf(x1.x, gr[4], br[4]), 0.0f);
            vb.y = m * fmaxf(fmaf(x1.y, gr[5], br[5]), 0.0f);
            vb.z = m * fmaxf(fmaf(x1.z, gr[6], br[6]), 0.0f);
            vb.w = m * fmaxf(fmaf(x1.w, gr[7], br[7]), 0.0f);
        }
        xsa[i] = va; xsb[i] = vb;
    }
    #pragma unroll
    for (int c = 0; c < 8; ++c) { gr[c] = g2[c]; br[c] = bb2[c]; }
    __syncthreads();

    // phase 2: conv1 over the 1-halo region; bnrelu2 fused into the store
    for (int pos = tid; pos < HA; pos += 256) {
        int py = pos / HT, px = pos % HT;
        float mc = msh[(py + 1) * XT + px + 1];
        float acc[8];
        #pragma unroll
        for (int co = 0; co < 8; ++co) acc[co] = 0.0f;
        if (mc > 0.0f) {
            #pragma unroll
            for (int kh = 0; kh < 3; ++kh)
                #pragma unroll
                for (int kw = 0; kw < 3; ++kw) {
                    int pix = (py + kh) * XT + px + kw;
                    float4 a = xsa[pix], c4 = xsb[pix];      // 2x ds_read_b128
                    const float* wp = w1 + (kh * 3 + kw) * 64;  // wave-uniform -> s_load
                    #pragma unroll
                    for (int co = 0; co < 8; ++co) {
                        float s = fmaf(a.x,  wp[co],      acc[co]);
                        s = fmaf(a.y,  wp[8  + co], s);
                        s = fmaf(a.z,  wp[16 + co], s);
                        s = fmaf(a.w,  wp[24 + co], s);
                        s = fmaf(c4.x, wp[32 + co], s);
                        s = fmaf(c4.y, wp[40 + co], s);
                        s = fmaf(c4.z, wp[48 + co], s);
                        acc[co] = fmaf(c4.w, wp[56 + co], s);
                    }
                }
        }
        float4 ha, hb;
        ha.x = mc * fmaxf(fmaf(acc[0] * mc, gr[0], br[0]), 0.0f);
        ha.y = mc * fmaxf(fmaf(acc[1] * mc, gr[1], br[1]), 0.0f);
        ha.z = mc * fmaxf(fmaf(acc[2] * mc, gr[2], br[2]), 0.0f);
        ha.w = mc * fmaxf(fmaf(acc[3] * mc, gr[3], br[3]), 0.0f);
        hb.x = mc * fmaxf(fmaf(acc[4] * mc, gr[4], br[4]), 0.0f);
        hb.y = mc * fmaxf(fmaf(acc[5] * mc, gr[5], br[5]), 0.0f);
        hb.z = mc * fmaxf(fmaf(acc[6] * mc, gr[6], br[6]), 0.0f);
        hb.w = mc * fmaxf(fmaf(acc[7] * mc, gr[7], br[7]), 0.0f);
        h1a[pos] = ha; h1b[pos] = hb;                       // 2x ds_write_b128
    }
    __syncthreads();

    // phase 3: conv2 at the TILE x TILE center + residual (re-read x, L2-hot)
    for (int pos = tid; pos < TILE * TILE; pos += 256) {
        int ty = pos / TILE, tx = pos % TILE;
        int gy = r0 + ty, gx = c0 + tx;
        if (gy < H && gx < H) {
            float mo = msh[(ty + 2) * XT + tx + 2];
            float acc[8];
            #pragma unroll
            for (int co = 0; co < 8; ++co) acc[co] = 0.0f;
            if (mo > 0.0f) {
                #pragma unroll
                for (int kh = 0; kh < 3; ++kh)
                    #pragma unroll
                    for (int kw = 0; kw < 3; ++kw) {
                        int pix = (ty + kh) * HT + tx + kw;
                        float4 a = h1a[pix], c4 = h1b[pix];
                        const float* wp = w2 + (kh * 3 + kw) * 64;
                        #pragma unroll
                        for (int co = 0; co < 8; ++co) {
                            float s = fmaf(a.x,  wp[co],      acc[co]);
                            s = fmaf(a.y,  wp[8  + co], s);
                            s = fmaf(a.z,  wp[16 + co], s);
                            s = fmaf(a.w,  wp[24 + co], s);
                            s = fmaf(c4.x, wp[32 + co], s);
                            s = fmaf(c4.y, wp[40 + co], s);
                            s = fmaf(c4.z, wp[48 + co], s);
                            acc[co] = fmaf(c4.w, wp[56 + co], s);
                        }
                    }
            }
            const float* rp = in + ((size_t)(b * H + gy) * H + gx) * 8;
            float* op = out + ((size_t)(b * H + gy) * H + gx) * 8;
            float4 ra = *(const float4*)rp;
            float4 rb = *(const float4*)(rp + 4);
            float4 oa, ob;
            oa.x = fmaf(acc[0], mo, ra.x);
            oa.y = fmaf(acc[1], mo, ra.y);
            oa.z = fmaf(acc[2], mo, ra.z);
            oa.w = fmaf(acc[3], mo, ra.w);
            ob.x = fmaf(acc[4], mo, rb.x);
            ob.y = fmaf(acc[5], mo, rb.y);
            ob.z = fmaf(acc[6], mo, rb.z);
            ob.w = fmaf(acc[7], mo, rb.w);
            *(float4*)op = oa;
            *(float4*)(op + 4) = ob;
        }
    }
}

// Fused conv: optionally bnrelu on input, conv, * mOut, [+ res].
// Tap-serial form: ~36 VGPR, occupancy-driven latency hiding.
template <int K, int CIN, int COUT, int COT, bool BN, bool RES>
__global__ __launch_bounds__(256) void fconv_kernel(
    const float* __restrict__ in, const float* __restrict__ w,
    const float* __restrict__ g, const float* __restrict__ bbn,
    const float* __restrict__ mIn, const float* __restrict__ mOut,
    const float* __restrict__ res, float* __restrict__ out,
    int Hin, int Hout, int stride, int pad) {
    const int Win = Hin, Wout = Hout;
    int npix = BATCH * Hout * Wout;
    int opix = blockIdx.x * 256 + threadIdx.x;
    if (opix >= npix) return;
    int co0 = blockIdx.y * COT;
    int wo = opix % Wout;
    int t = opix / Wout;
    int ho = t % Hout;
    int b  = t / Hout;

    float mo = mOut[opix];
    float* op = out + (size_t)opix * COUT + co0;
    if (mo <= 0.0f) {
        #pragma unroll
        for (int j = 0; j < COT; j += 4) {
            float4 r4 = RES ? *(const float4*)(res + (size_t)opix * COUT + co0 + j)
                            : make_float4(0,0,0,0);
            *(float4*)(op + j) = r4;
        }
        return;
    }
    float acc[COT];
    #pragma unroll
    for (int j = 0; j < COT; ++j) acc[j] = 0.0f;

    #pragma unroll
    for (int kh = 0; kh < K; ++kh) {
        int ih = ho * stride + kh - pad;
        if ((unsigned)ih >= (unsigned)Hin) continue;
        #pragma unroll
        for (int kw = 0; kw < K; ++kw) {
            int iw = wo * stride + kw - pad;
            if ((unsigned)iw >= (unsigned)Win) continue;
            int ipix = (b * Hin + ih) * Win + iw;
            float mi = 1.0f;
            if (BN) { mi = mIn[ipix]; if (mi <= 0.0f) continue; }
            const float* ip = in + (size_t)ipix * CIN;
            const float* wp = w + (kh * K + kw) * CIN * COUT + co0;
            #pragma unroll
            for (int ci = 0; ci < CIN; ci += 4) {
                float4 xv = *(const float4*)(ip + ci);
                if (BN) {
                    xv.x = mi * fmaxf(fmaf(xv.x, g[ci],     bbn[ci]),     0.0f);
                    xv.y = mi * fmaxf(fmaf(xv.y, g[ci + 1], bbn[ci + 1]), 0.0f);
                    xv.z = mi * fmaxf(fmaf(xv.z, g[ci + 2], bbn[ci + 2]), 0.0f);
                    xv.w = mi * fmaxf(fmaf(xv.w, g[ci + 3], bbn[ci + 3]), 0.0f);
                }
                #pragma unroll
                for (int j = 0; j < COT; ++j) {
                    acc[j] = fmaf(xv.x, wp[(ci    ) * COUT + j], acc[j]);
                    acc[j] = fmaf(xv.y, wp[(ci + 1) * COUT + j], acc[j]);
                    acc[j] = fmaf(xv.z, wp[(ci + 2) * COUT + j], acc[j]);
                    acc[j] = fmaf(xv.w, wp[(ci + 3) * COUT + j], acc[j]);
                }
            }
        }
    }
    #pragma unroll
    for (int j = 0; j < COT; j += 4) {
        float4 o4;
        o4.x = acc[j] * mo; o4.y = acc[j+1] * mo; o4.z = acc[j+2] * mo; o4.w = acc[j+3] * mo;
        if (RES) {
            float4 r4 = *(const float4*)(res + (size_t)opix * COUT + co0 + j);
            o4.x += r4.x; o4.y += r4.y; o4.z += r4.z; o4.w += r4.w;
        }
        *(float4*)(op + j) = o4;
    }
}

// Fused downsample stage, BOTH paths in one pass (input/mask loaded once):
//   m2 = maxpool3x3s2(mIn)  (written by blockIdx.y == 0)
//   outR = conv3x3s2(x) * m2 ; outA = conv3x3s2(bnrelu(x)) * m2
template <int CIN, int COUT, int COT>
__global__ __launch_bounds__(256) void strided_both_kernel(
    const float* __restrict__ in,
    const float* __restrict__ wR, const float* __restrict__ wA,
    const float* __restrict__ g, const float* __restrict__ bbn,
    const float* __restrict__ mIn, float* __restrict__ mOutBuf,
    float* __restrict__ outR, float* __restrict__ outA,
    int Hin, int Hout) {
    int npix = BATCH * Hout * Hout;
    int opix = blockIdx.x * 256 + threadIdx.x;
    if (opix >= npix) return;
    int co0 = blockIdx.y * COT;
    int wo = opix % Hout;
    int t = opix / Hout;
    int ho = t % Hout;
    int b  = t / Hout;

    float accR[COT], accA[COT];
    #pragma unroll
    for (int j = 0; j < COT; ++j) { accR[j] = 0.0f; accA[j] = 0.0f; }
    float m2 = 0.0f;

    #pragma unroll
    for (int kh = 0; kh < 3; ++kh) {
        int ih = 2 * ho + kh;
        #pragma unroll
        for (int kw = 0; kw < 3; ++kw) {
            int iw = 2 * wo + kw;
            int ipix = (b * Hin + ih) * Hin + iw;
            float mi = mIn[ipix];
            if (mi <= 0.0f) continue;
            m2 = fmaxf(m2, mi);
            const float* ip  = in + (size_t)ipix * CIN;
            const float* wpR = wR + (kh * 3 + kw) * CIN * COUT + co0;
            const float* wpA = wA + (kh * 3 + kw) * CIN * COUT + co0;
            #pragma unroll
            for (int ci = 0; ci < CIN; ci += 4) {
                float4 xv = *(const float4*)(ip + ci);
                float4 xa;
                xa.x = mi * fmaxf(fmaf(xv.x, g[ci],     bbn[ci]),     0.0f);
                xa.y = mi * fmaxf(fmaf(xv.y, g[ci + 1], bbn[ci + 1]), 0.0f);
                xa.z = mi * fmaxf(fmaf(xv.z, g[ci + 2], bbn[ci + 2]), 0.0f);
                xa.w = mi * fmaxf(fmaf(xv.w, g[ci + 3], bbn[ci + 3]), 0.0f);
                #pragma unroll
                for (int j = 0; j < COT; ++j) {
                    accR[j] = fmaf(xv.x, wpR[(ci    ) * COUT + j], accR[j]);
                    accR[j] = fmaf(xv.y, wpR[(ci + 1) * COUT + j], accR[j]);
                    accR[j] = fmaf(xv.z, wpR[(ci + 2) * COUT + j], accR[j]);
                    accR[j] = fmaf(xv.w, wpR[(ci + 3) * COUT + j], accR[j]);
                    accA[j] = fmaf(xa.x, wpA[(ci    ) * COUT + j], accA[j]);
                    accA[j] = fmaf(xa.y, wpA[(ci + 1) * COUT + j], accA[j]);
                    accA[j] = fmaf(xa.z, wpA[(ci + 2) * COUT + j], accA[j]);
                    accA[j] = fmaf(xa.w, wpA[(ci + 3) * COUT + j], accA[j]);
                }
            }
        }
    }
    if (blockIdx.y == 0) mOutBuf[opix] = m2;
    float* opR = outR + (size_t)opix * COUT + co0;
    float* opA = outA + (size_t)opix * COUT + co0;
    #pragma unroll
    for (int j = 0; j < COT; j += 4) {
        *(float4*)(opR + j) = make_float4(accR[j] * m2, accR[j+1] * m2, accR[j+2] * m2, accR[j+3] * m2);
        *(float4*)(opA + j) = make_float4(accA[j] * m2, accA[j+1] * m2, accA[j+2] * m2, accA[j+3] * m2);
    }
}

// conv_last: 5x5 VALID conv (12,12,32)->(8,8,64) with bnrelu(g16,b16,m1) fused
// on the input. K-split over kh; partials summed in bn_tr.
__global__ __launch_bounds__(256) void convlast_kernel(
    const float* __restrict__ in,      // (128,12,12,32)
    const float* __restrict__ w,       // (5,5,32,64)
    const float* __restrict__ g, const float* __restrict__ bb,
    const float* __restrict__ mIn,     // (128,12,12)
    float* __restrict__ part) {        // (5,128,8,8,64)
    __shared__ float xs[32 * 97];      // planar [ci][row*12+col], pad to 97
    __shared__ float ws[5 * 32 * 64];  // [kw][ci][co] slice for this kh
    int b   = blockIdx.x;
    int kh  = blockIdx.y;
    int tid = threadIdx.x;
    for (int i = tid; i < 8 * 12 * 32; i += 256) {
        int ci = i & 31;
        int p  = i >> 5;                     // row*12+col, 0..95
        int gpix = (b * 12 + kh + p / 12) * 12 + (p % 12);
        float m = mIn[gpix];
        float v = 0.0f;
        if (m > 0.0f) v = fmaxf(fmaf(in[(size_t)gpix * 32 + ci], g[ci], bb[ci]), 0.0f);
        xs[ci * 97 + p] = v;
    }
    {
        const float4* src = (const float4*)(w + kh * (5 * 32 * 64));
        float4* dst = (float4*)ws;
        for (int i = tid; i < 5 * 32 * 64 / 4; i += 256) dst[i] = src[i];
    }
    __syncthreads();

    int px = tid & 63;            // output pixel (ho*8+wo)
    int cg = tid >> 6;            // co group of 16
    int ho = px >> 3, wo = px & 7;
    float acc[16];
    #pragma unroll
    for (int j = 0; j < 16; ++j) acc[j] = 0.0f;
    #pragma unroll
    for (int kw = 0; kw < 5; ++kw) {
        const float* xp = xs + ho * 12 + wo + kw;
        const float* wp = ws + kw * (32 * 64) + cg * 16;
        #pragma unroll
        for (int ci = 0; ci < 32; ++ci) {
            float xv = xp[ci * 97];
            const float* wr = wp + ci * 64;        // wave-uniform -> LDS broadcast
            #pragma unroll
            for (int j = 0; j < 16; j += 4) {
                float4 w4 = *(const float4*)(wr + j);
                acc[j]     = fmaf(xv, w4.x, acc[j]);
                acc[j + 1] = fmaf(xv, w4.y, acc[j + 1]);
                acc[j + 2] = fmaf(xv, w4.z, acc[j + 2]);
                acc[j + 3] = fmaf(xv, w4.w, acc[j + 3]);
            }
        }
    }
    float* op = part + ((((size_t)kh * BATCH + b) * 64 + px) * 64) + cg * 16;
    #pragma unroll
    for (int j = 0; j < 16; j += 4)
        *(float4*)(op + j) = make_float4(acc[j], acc[j+1], acc[j+2], acc[j+3]);
}

// sum 5 kh-partials + bnrelu(g17,b17,m0) + flatten to NCHW-flat: xt[b][c*64+hw]
__global__ __launch_bounds__(256) void bn_tr_kernel(
    const float* __restrict__ part, const float* __restrict__ m,
    const float* __restrict__ g, const float* __restrict__ bb,
    float* __restrict__ xt) {
    int tid = blockIdx.x * 256 + threadIdx.x;
    if (tid >= BATCH * 4096) return;
    int c = tid & 63, hw = (tid >> 6) & 63, b = tid >> 12;
    float s = 0.0f;
    #pragma unroll
    for (int k = 0; k < 5; ++k)
        s += part[(((size_t)k * BATCH + b) * 64 + hw) * 64 + c];
    float v = m[b * 64 + hw] * fmaxf(fmaf(s, g[c], bb[c]), 0.0f);
    xt[((size_t)b << 12) + c * 64 + hw] = v;
}

__global__ void pool_kernel(const float* __restrict__ in, float* __restrict__ out,
                            int Hin, int Win, int Hout, int Wout, int win, int stride) {
    int tid = blockIdx.x * blockDim.x + threadIdx.x;
    int total = BATCH * Hout * Wout;
    if (tid >= total) return;
    int wo = tid % Wout;
    int p = tid / Wout;
    int ho = p % Hout;
    int b  = p / Hout;
    float mx = 0.0f;
    for (int i = 0; i < win; ++i)
        for (int j = 0; j < win; ++j)
            mx = fmaxf(mx, in[(b * Hin + ho * stride + i) * Win + wo * stride + j]);
    out[tid] = mx;
}

// C[128,100] += xt[128,4096] . wl[100,4096]^T, split-K with atomics.
__global__ __launch_bounds__(256) void linear_gemm_kernel(
    const float* __restrict__ xt, const float* __restrict__ wl,
    float* __restrict__ out) {
    int o = blockIdx.x;
    int half = threadIdx.x >> 7;
    int b = threadIdx.x & 127;
    int k0 = blockIdx.y * 512 + half * 256;
    const float* xp = xt + ((size_t)b << 12) + k0;
    const float* wp = wl + o * 4096 + k0;
    float acc = 0.0f;
    #pragma unroll 16
    for (int k = 0; k < 256; k += 4) {
        float4 xv = *(const float4*)(xp + k);
        float4 wv = *(const float4*)(wp + k);
        acc = fmaf(xv.x, wv.x, acc); acc = fmaf(xv.y, wv.y, acc);
        acc = fmaf(xv.z, wv.z, acc); acc = fmaf(xv.w, wv.w, acc);
    }
    atomicAdd(&out[b * 100 + o], acc);
}

template <int K, int CIN, int COUT, int COT, bool BN, bool RES>
static inline void fconv(hipStream_t s, const float* in, const float* w,
                         const float* g, const float* bbn,
                         const float* mIn, const float* mOut, const float* res,
                         float* out, int Hin, int Hout, int stride, int pad) {
    int npix = BATCH * Hout * Hout;
    dim3 grid((npix + 255) / 256, COUT / COT);
    fconv_kernel<K, CIN, COUT, COT, BN, RES><<<grid, 256, 0, s>>>(
        in, w, g, bbn, mIn, mOut, res, out, Hin, Hout, stride, pad);
}

template <int CIN, int COUT, int COT>
static inline void strided_both(hipStream_t s, const float* in, const float* wR, const float* wA,
                                const float* g, const float* bbn, const float* mIn,
                                float* mOutBuf, float* outR, float* outA, int Hin, int Hout) {
    int npix = BATCH * Hout * Hout;
    dim3 grid((npix + 255) / 256, COUT / COT);
    strided_both_kernel<CIN, COUT, COT><<<grid, 256, 0, s>>>(
        in, wR, wA, g, bbn, mIn, mOutBuf, outR, outA, Hin, Hout);
}

extern "C" void kernel_launch(void* const* d_in, const int* in_sizes, int n_in,
                              void* d_out, int out_size, void* d_ws, size_t ws_size,
                              hipStream_t stream) {
    const int*   loc   = (const int*)d_in[0];
    const int*   bidx  = (const int*)d_in[1];
    const float* feat  = (const float*)d_in[2];
    const float* gamma = (const float*)d_in[3];
    const float* beta  = (const float*)d_in[4];
    const float* Wconv0 = (const float*)d_in[5];
    const float* Wc1a = (const float*)d_in[6];
    const float* Wc1b = (const float*)d_in[7];
    const float* Wc2a = (const float*)d_in[8];
    const float* Wc2b = (const float*)d_in[9];
    const float* Wc3a = (const float*)d_in[10];
    const float* Wc3b = (const float*)d_in[11];
    const float* Wc3r = (const float*)d_in[12];
    const float* Wc4a = (const float*)d_in[13];
    const float* Wc4b = (const float*)d_in[14];
    const float* Wc5a = (const float*)d_in[15];
    const float* Wc5b = (const float*)d_in[16];
    const float* Wc5r = (const float*)d_in[17];
    const float* Wc6a = (const float*)d_in[18];
    const float* Wc6b = (const float*)d_in[19];
    const float* Wc7a = (const float*)d_in[20];
    const float* Wc7b = (const float*)d_in[21];
    const float* Wc7r = (const float*)d_in[22];
    const float* Wc8a = (const float*)d_in[23];
    const float* Wc8b = (const float*)d_in[24];
    const float* Wlast = (const float*)d_in[25];
    const float* wlin  = (const float*)d_in[26];

    const size_t SZB = (size_t)BATCH * 103 * 103 * 8;
    const size_t SZM = (size_t)BATCH * 103 * 103;
    float* b0 = (float*)d_ws;
    float* b1 = b0 + SZB;
    float* b2 = b1 + SZB;
    float* m0 = b2 + SZB;
    float* m1 = m0 + SZM;

    const float* G[18];
    const float* Bt[18];
    for (int i = 0; i < 18; ++i) { G[i] = gamma + OFFS[i]; Bt[i] = beta + OFFS[i]; }

    // scatter into xs(b1), ms(b2)
    {
        int n = BATCH * S * S;
        zero2_kernel<<<(n / 4 + 255) / 256, 256, 0, stream>>>((float4*)b1, (float4*)b2, n / 4);
        scatter_kernel<<<(NPTS + 255) / 256, 256, 0, stream>>>(loc, bidx, feat, b1, b2);
        int total = BATCH * 103 * 103;
        conv0_pool_kernel<<<(total + 255) / 256, 256, 0, stream>>>(b1, b2, Wconv0, b0, m0);
    }
    // x = b0 (103,103,8), mask = m0

    // c1, c2: fused residual blocks, float4-planar LDS (b128 reads)
    resblock8f4_kernel<16, 7><<<dim3(7 * 7 * BATCH), 256, 0, stream>>>(
        b0, m0, Wc1a, Wc1b, G[0], Bt[0], G[1], Bt[1], b1, 103);
    resblock8f4_kernel<16, 7><<<dim3(7 * 7 * BATCH), 256, 0, stream>>>(
        b1, m0, Wc2a, Wc2b, G[2], Bt[2], G[3], Bt[3], b2, 103);
    // x = b2
    // c3 (stride2, 103->51, 8->16): both paths fused, input read once
    strided_both<8, 16, 16>(stream, b2, Wc3r, Wc3a, G[4], Bt[4], m0, m1, b0, b1, 103, 51);
    fconv<3, 16, 16, 8, true, true >(stream, b1, Wc3b, G[5], Bt[5], m1, m1, b0, b2, 51, 51, 1, 1);
    // x = b2, mask = m1
    // c4 (fconv pair: round-4 form; fconv16_lds was LDS-pipe-bound and neutral-negative)
    fconv<3, 16, 16, 8, true, false>(stream, b2, Wc4a, G[6], Bt[6], m1, m1, nullptr, b0, 51, 51, 1, 1);
    fconv<3, 16, 16, 8, true, true >(stream, b0, Wc4b, G[7], Bt[7], m1, m1, b2,      b1, 51, 51, 1, 1);
    // x = b1
    // c5 (stride2, 51->25, 16->24): both paths fused, COT=12
    strided_both<16, 24, 12>(stream, b1, Wc5r, Wc5a, G[8], Bt[8], m1, m0, b0, b2, 51, 25);
    fconv<3, 24, 24, 8, true, true >(stream, b2, Wc5b, G[9], Bt[9], m0, m0, b0, b1, 25, 25, 1, 1);
    // x = b1, mask = m0
    // c6 (fconv pair)
    fconv<3, 24, 24, 8, true, false>(stream, b1, Wc6a, G[10], Bt[10], m0, m0, nullptr, b0, 25, 25, 1, 1);
    fconv<3, 24, 24, 8, true, true >(stream, b0, Wc6b, G[11], Bt[11], m0, m0, b1,      b2, 25, 25, 1, 1);
    // x = b2
    // c7 (stride2, 25->12, 24->32): both paths fused, COT=8
    strided_both<24, 32, 8>(stream, b2, Wc7r, Wc7a, G[12], Bt[12], m0, m1, b0, b1, 25, 12);
    fconv<3, 32, 32, 4, true, true >(stream, b1, Wc7b, G[13], Bt[13], m1, m1, b0, b2, 12, 12, 1, 1);
    // x = b2, mask = m1
    // c8
    fconv<3, 32, 32, 4, true, false>(stream, b2, Wc8a, G[14], Bt[14], m1, m1, nullptr, b0, 12, 12, 1, 1);
    fconv<3, 32, 32, 4, true, true >(stream, b0, Wc8b, G[15], Bt[15], m1, m1, b2,      b1, 12, 12, 1, 1);
    // x = b1
    // tail: pooled mask, LDS-tiled conv_last (kh-split partials in b0), fused sum+bn+tr
    pool_kernel<<<(BATCH * 64 + 255) / 256, 256, 0, stream>>>(m1, m0, 12, 12, 8, 8, 5, 1);
    convlast_kernel<<<dim3(BATCH, 5), 256, 0, stream>>>(b1, Wlast, G[16], Bt[16], m1, b0);
    bn_tr_kernel<<<(BATCH * 4096 + 255) / 256, 256, 0, stream>>>(b0, m0, G[17], Bt[17], b2);
    zero_kernel<<<(BATCH * 100 + 255) / 256, 256, 0, stream>>>((float*)d_out, BATCH * 100);
    linear_gemm_kernel<<<dim3(100, 8), 256, 0, stream>>>(b2, wlin, (float*)d_out);
}